// Round 1
// baseline (565.709 us; speedup 1.0000x reference)
//
#include <hip/hip_runtime.h>
#include <hip/hip_bf16.h>

#define N_NODES 50000
#define N_EDGES 800000
#define TOT_E   (N_EDGES + N_NODES)

typedef __attribute__((ext_vector_type(8))) short short8;
typedef __attribute__((ext_vector_type(4))) float f32x4;

__device__ __forceinline__ unsigned short f2bf(float f) {
  union { float f; unsigned int u; } x; x.f = f;
  unsigned int u = x.u;
  unsigned int r = (u + 0x7FFFu + ((u >> 16) & 1u)) >> 16;  // RNE
  return (unsigned short)r;
}

// ---- setup kernels -------------------------------------------------------

__global__ void init_kernel(int* __restrict__ deg, float* __restrict__ sums1,
                            float* __restrict__ sums2) {
  int i = blockIdx.x * 256 + threadIdx.x;
  if (i < N_NODES) deg[i] = 1;                 // self-loop
  if (i < 256) { sums1[i] = 0.f; sums2[i] = 0.f; }
}

// edge_index dtype detection: if stored as int64 (values < 2^31), every odd
// int32 word of the first 64 entries is 0. flag=1 => int64 layout.
__global__ void detect_kernel(const int* __restrict__ ei, int* __restrict__ flag) {
  int t = threadIdx.x;  // 64 threads
  int v = ei[2 * t + 1];
  unsigned long long b = __ballot(v != 0);
  if (t == 0) flag[0] = (b == 0ULL) ? 1 : 0;
}

__global__ void count_kernel(const int* __restrict__ ei, const int* __restrict__ flag,
                             int* __restrict__ deg) {
  int e = blockIdx.x * 256 + threadIdx.x;
  if (e >= N_EDGES) return;
  int d = flag[0] ? ei[2 * (N_EDGES + e)] : ei[N_EDGES + e];
  atomicAdd(&deg[d], 1);
}

__global__ __launch_bounds__(1024) void scan_kernel(const int* __restrict__ deg,
    int* __restrict__ rs, int* __restrict__ cur, float* __restrict__ dinv) {
  __shared__ int tmp[1024];
  __shared__ int carry;
  int tid = threadIdx.x;
  if (tid == 0) carry = 0;
  for (int base = 0; base < N_NODES; base += 1024) {
    int i = base + tid;
    int d = (i < N_NODES) ? deg[i] : 0;
    tmp[tid] = d;
    __syncthreads();
    int v = tmp[tid];
    for (int off = 1; off < 1024; off <<= 1) {
      int add = (tid >= off) ? tmp[tid - off] : 0;
      __syncthreads();
      v += add;
      tmp[tid] = v;
      __syncthreads();
    }
    int c = carry;
    if (i < N_NODES) {
      int excl = c + v - d;
      rs[i] = excl;
      cur[i] = excl;
      dinv[i] = rsqrtf((float)d);   // deg >= 1 always (self-loop)
    }
    __syncthreads();
    if (tid == 1023) carry = c + v;
    __syncthreads();
  }
  if (tid == 0) rs[N_NODES] = carry;
}

__global__ void fill_kernel(const int* __restrict__ ei, const int* __restrict__ flag,
                            int* __restrict__ cur, int* __restrict__ csr) {
  int e = blockIdx.x * 256 + threadIdx.x;
  if (e >= TOT_E) return;
  int s, d;
  if (e < N_EDGES) {
    if (flag[0]) { s = ei[2 * e]; d = ei[2 * (N_EDGES + e)]; }
    else         { s = ei[e];     d = ei[N_EDGES + e]; }
  } else {
    s = d = e - N_EDGES;  // self-loop
  }
  int pos = atomicAdd(&cur[d], 1);
  csr[pos] = s;
}

__global__ void f2bf_kernel(const float* __restrict__ in, unsigned short* __restrict__ out) {
  long i = (long)(blockIdx.x * 256 + threadIdx.x) * 4;
  if (i >= (long)N_NODES * 128) return;
  float4 v = *(const float4*)(in + i);
  union { unsigned short u[4]; unsigned long long ll; } o;
  o.u[0] = f2bf(v.x); o.u[1] = f2bf(v.y); o.u[2] = f2bf(v.z); o.u[3] = f2bf(v.w);
  *(unsigned long long*)(out + i) = o.ll;
}

// ---- dense matmul: H[n][o] = sum_k Xb[n][k] * W[o][k]  (bf16 MFMA) -------

template <int OUT>
__global__ __launch_bounds__(256) void mm_kernel(const unsigned short* __restrict__ Xb,
    const float* __restrict__ W, float* __restrict__ Hout) {
  constexpr int K = 128;
  constexpr int LDW = K + 8;  // pad to break LDS bank aliasing on b128 reads
  __shared__ __align__(16) unsigned short Wl[OUT * LDW];
  int tid = threadIdx.x;
  for (int i = tid; i < OUT * K; i += 256)
    Wl[(i >> 7) * LDW + (i & 127)] = f2bf(W[i]);
  __syncthreads();

  int lane = tid & 63;
  int wv = tid >> 6;
  int m = lane & 15, q = lane >> 4;
  long n0 = (long)blockIdx.x * 64 + wv * 16;
  long arow = n0 + m; if (arow > N_NODES - 1) arow = N_NODES - 1;  // clamp; dead rows discarded
  const unsigned short* xr = Xb + arow * K + q * 8;
  short8 a0 = *(const short8*)(xr);
  short8 a1 = *(const short8*)(xr + 32);
  short8 a2 = *(const short8*)(xr + 64);
  short8 a3 = *(const short8*)(xr + 96);

  f32x4 acc[OUT / 16];
#pragma unroll
  for (int t = 0; t < OUT / 16; t++) acc[t] = (f32x4){0.f, 0.f, 0.f, 0.f};

#pragma unroll
  for (int ot = 0; ot < OUT / 16; ot++) {
    const unsigned short* wrow = Wl + (size_t)(ot * 16 + m) * LDW + q * 8;
    short8 b0 = *(const short8*)(wrow);
    short8 b1 = *(const short8*)(wrow + 32);
    short8 b2 = *(const short8*)(wrow + 64);
    short8 b3 = *(const short8*)(wrow + 96);
    acc[ot] = __builtin_amdgcn_mfma_f32_16x16x32_bf16(a0, b0, acc[ot], 0, 0, 0);
    acc[ot] = __builtin_amdgcn_mfma_f32_16x16x32_bf16(a1, b1, acc[ot], 0, 0, 0);
    acc[ot] = __builtin_amdgcn_mfma_f32_16x16x32_bf16(a2, b2, acc[ot], 0, 0, 0);
    acc[ot] = __builtin_amdgcn_mfma_f32_16x16x32_bf16(a3, b3, acc[ot], 0, 0, 0);
  }

#pragma unroll
  for (int ot = 0; ot < OUT / 16; ot++) {
#pragma unroll
    for (int r = 0; r < 4; r++) {
      long n = n0 + q * 4 + r;            // D: row = quad*4 + reg, col = lane&15
      if (n < N_NODES) Hout[n * OUT + ot * 16 + m] = acc[ot][r];
    }
  }
}

// ---- aggregation: out[i] = dinv[i] * sum_j dinv[s_j] * H[s_j] + bias -----

__global__ __launch_bounds__(256) void agg128_kernel(const float* __restrict__ H,
    const int* __restrict__ rs, const int* __restrict__ csr, const float* __restrict__ dinv,
    const float* __restrict__ bias, float* __restrict__ out) {
  int lane = threadIdx.x & 63;
  int node = blockIdx.x * 4 + (threadIdx.x >> 6);
  if (node >= N_NODES) return;
  int beg = rs[node], end = rs[node + 1];
  int c = lane * 2;
  float ax = 0.f, ay = 0.f, bx = 0.f, by = 0.f;
  int j = beg;
  for (; j + 2 <= end; j += 2) {           // 2-edge unroll for load ILP
    int s0 = csr[j], s1 = csr[j + 1];
    float w0 = dinv[s0], w1 = dinv[s1];
    float2 v0 = *(const float2*)(H + (size_t)s0 * 128 + c);
    float2 v1 = *(const float2*)(H + (size_t)s1 * 128 + c);
    ax += w0 * v0.x; ay += w0 * v0.y;
    bx += w1 * v1.x; by += w1 * v1.y;
  }
  if (j < end) {
    int s0 = csr[j];
    float w0 = dinv[s0];
    float2 v0 = *(const float2*)(H + (size_t)s0 * 128 + c);
    ax += w0 * v0.x; ay += w0 * v0.y;
  }
  float di = dinv[node];
  out[(size_t)node * 128 + c]     = (ax + bx) * di + bias[c];
  out[(size_t)node * 128 + c + 1] = (ay + by) * di + bias[c + 1];
}

__global__ __launch_bounds__(256) void agg64_kernel(const float* __restrict__ H,
    const int* __restrict__ rs, const int* __restrict__ csr, const float* __restrict__ dinv,
    const float* __restrict__ bias, float* __restrict__ out) {
  int lane = threadIdx.x & 63;
  int node = blockIdx.x * 4 + (threadIdx.x >> 6);
  if (node >= N_NODES) return;
  int beg = rs[node], end = rs[node + 1];
  float a = 0.f, b = 0.f;
  int j = beg;
  for (; j + 2 <= end; j += 2) {
    int s0 = csr[j], s1 = csr[j + 1];
    float w0 = dinv[s0], w1 = dinv[s1];
    a += w0 * H[(size_t)s0 * 64 + lane];
    b += w1 * H[(size_t)s1 * 64 + lane];
  }
  if (j < end) {
    int s0 = csr[j];
    a += dinv[s0] * H[(size_t)s0 * 64 + lane];
  }
  out[(size_t)node * 64 + lane] = (a + b) * dinv[node] + bias[lane];
}

// ---- BN stats + fused BN/ReLU/bf16-cast ----------------------------------

__global__ __launch_bounds__(128) void stats_kernel(const float* __restrict__ H,
                                                    float* __restrict__ sums) {
  int c = threadIdx.x;  // 128
  float s = 0.f, s2 = 0.f;
  for (int r = blockIdx.x; r < N_NODES; r += gridDim.x) {
    float v = H[(size_t)r * 128 + c];
    s += v; s2 += v * v;
  }
  atomicAdd(&sums[c], s);
  atomicAdd(&sums[128 + c], s2);
}

__global__ void bnrelu_kernel(const float* __restrict__ H, const float* __restrict__ sums,
    const float* __restrict__ g, const float* __restrict__ bt,
    unsigned short* __restrict__ Xb) {
  long i = (long)(blockIdx.x * 256 + threadIdx.x) * 4;
  if (i >= (long)N_NODES * 128) return;
  int c = (int)(i & 127);
  float4 v = *(const float4*)(H + i);
  float vv[4] = {v.x, v.y, v.z, v.w};
  const float inv_n = 1.0f / (float)N_NODES;
  union { unsigned short u[4]; unsigned long long ll; } o;
#pragma unroll
  for (int t = 0; t < 4; t++) {
    int ch = c + t;
    float mean = sums[ch] * inv_n;
    float var  = sums[128 + ch] * inv_n - mean * mean;
    float sc = g[ch] * rsqrtf(var + 1e-5f);
    float sh = bt[ch] - mean * sc;
    float r = vv[t] * sc + sh;
    r = r > 0.f ? r : 0.f;
    o.u[t] = f2bf(r);
  }
  *(unsigned long long*)(Xb + i) = o.ll;
}

// ---- driver --------------------------------------------------------------

extern "C" void kernel_launch(void* const* d_in, const int* in_sizes, int n_in,
                              void* d_out, int out_size, void* d_ws, size_t ws_size,
                              hipStream_t stream) {
  const float* x   = (const float*)d_in[0];
  const int*   ei  = (const int*)d_in[1];
  const float* W1  = (const float*)d_in[2];
  const float* b1  = (const float*)d_in[3];
  const float* W2  = (const float*)d_in[4];
  const float* b2  = (const float*)d_in[5];
  const float* W3  = (const float*)d_in[6];
  const float* b3  = (const float*)d_in[7];
  const float* g1  = (const float*)d_in[8];
  const float* bt1 = (const float*)d_in[9];
  const float* g2  = (const float*)d_in[10];
  const float* bt2 = (const float*)d_in[11];
  float* out = (float*)d_out;

  char* p = (char*)d_ws;
  auto carve = [&](size_t bytes) { char* r = p; p += (bytes + 255) & ~(size_t)255; return r; };
  int*   deg   = (int*)  carve((size_t)N_NODES * 4);
  int*   rs    = (int*)  carve((size_t)(N_NODES + 1) * 4);
  int*   cur   = (int*)  carve((size_t)N_NODES * 4);
  float* dinv  = (float*)carve((size_t)N_NODES * 4);
  int*   csr   = (int*)  carve((size_t)TOT_E * 4);
  float* sums1 = (float*)carve(256 * 4);
  float* sums2 = (float*)carve(256 * 4);
  int*   flag  = (int*)  carve(256);
  unsigned short* Xb = (unsigned short*)carve((size_t)N_NODES * 128 * 2);
  float* bufA  = (float*)carve((size_t)N_NODES * 128 * 4);
  float* bufB  = (float*)carve((size_t)N_NODES * 128 * 4);

  const int EW_BLOCKS = (N_NODES * 128 / 4 + 255) / 256;  // 6250

  init_kernel<<<(N_NODES + 255) / 256, 256, 0, stream>>>(deg, sums1, sums2);
  detect_kernel<<<1, 64, 0, stream>>>(ei, flag);
  count_kernel<<<(N_EDGES + 255) / 256, 256, 0, stream>>>(ei, flag, deg);
  scan_kernel<<<1, 1024, 0, stream>>>(deg, rs, cur, dinv);
  fill_kernel<<<(TOT_E + 255) / 256, 256, 0, stream>>>(ei, flag, cur, csr);
  f2bf_kernel<<<EW_BLOCKS, 256, 0, stream>>>(x, Xb);

  // layer 1
  mm_kernel<128><<<(N_NODES + 63) / 64, 256, 0, stream>>>(Xb, W1, bufA);
  agg128_kernel<<<(N_NODES + 3) / 4, 256, 0, stream>>>(bufA, rs, csr, dinv, b1, bufB);
  stats_kernel<<<512, 128, 0, stream>>>(bufB, sums1);
  bnrelu_kernel<<<EW_BLOCKS, 256, 0, stream>>>(bufB, sums1, g1, bt1, Xb);

  // layer 2
  mm_kernel<128><<<(N_NODES + 63) / 64, 256, 0, stream>>>(Xb, W2, bufA);
  agg128_kernel<<<(N_NODES + 3) / 4, 256, 0, stream>>>(bufA, rs, csr, dinv, b2, bufB);
  stats_kernel<<<512, 128, 0, stream>>>(bufB, sums2);
  bnrelu_kernel<<<EW_BLOCKS, 256, 0, stream>>>(bufB, sums2, g2, bt2, Xb);

  // layer 3 (128 -> 64), aggregate straight into d_out
  mm_kernel<64><<<(N_NODES + 63) / 64, 256, 0, stream>>>(Xb, W3, bufA);
  agg64_kernel<<<(N_NODES + 3) / 4, 256, 0, stream>>>(bufA, rs, csr, dinv, b3, out);
}

// Round 2
// 453.136 us; speedup vs baseline: 1.2484x; 1.2484x over previous
//
#include <hip/hip_runtime.h>
#include <hip/hip_bf16.h>

#define N_NODES 50000
#define N_EDGES 800000
#define TOT_E   (N_EDGES + N_NODES)
#define SCAN_NBLK ((N_NODES + 1023) / 1024)   // 49

typedef __attribute__((ext_vector_type(8))) short short8;
typedef __attribute__((ext_vector_type(4))) float f32x4;

__device__ __forceinline__ unsigned short f2bf(float f) {
  union { float f; unsigned int u; } x; x.f = f;
  unsigned int u = x.u;
  unsigned int r = (u + 0x7FFFu + ((u >> 16) & 1u)) >> 16;  // RNE
  return (unsigned short)r;
}
__device__ __forceinline__ float bf2f(unsigned int u16) {
  union { unsigned int u; float f; } x; x.u = u16 << 16; return x.f;
}

// ---- setup kernels -------------------------------------------------------

__global__ void init_kernel(int* __restrict__ deg, float* __restrict__ sums1,
                            float* __restrict__ sums2, int* __restrict__ rs) {
  int i = blockIdx.x * 256 + threadIdx.x;
  if (i < N_NODES) deg[i] = 1;                 // self-loop
  if (i < 256) { sums1[i] = 0.f; sums2[i] = 0.f; }
  if (i == 0) rs[N_NODES] = TOT_E;
}

// edge_index dtype detection: if stored as int64 (values < 2^31), every odd
// int32 word of the first 64 entries is 0. flag=1 => int64 layout.
__global__ void detect_kernel(const int* __restrict__ ei, int* __restrict__ flag) {
  int t = threadIdx.x;  // 64 threads
  int v = ei[2 * t + 1];
  unsigned long long b = __ballot(v != 0);
  if (t == 0) flag[0] = (b == 0ULL) ? 1 : 0;
}

__global__ void count_kernel(const int* __restrict__ ei, const int* __restrict__ flag,
                             int* __restrict__ deg) {
  int e = blockIdx.x * 256 + threadIdx.x;
  if (e >= N_EDGES) return;
  int d = flag[0] ? ei[2 * (N_EDGES + e)] : ei[N_EDGES + e];
  atomicAdd(&deg[d], 1);
}

// ---- 3-phase parallel exclusive scan of deg -> rs/cur, plus dinv ---------

__global__ __launch_bounds__(1024) void scan1_kernel(const int* __restrict__ deg,
    int* __restrict__ rs, float* __restrict__ dinv, int* __restrict__ partials) {
  int tid = threadIdx.x;
  int lane = tid & 63, wid = tid >> 6;   // 16 waves
  int i = blockIdx.x * 1024 + tid;
  int d = (i < N_NODES) ? deg[i] : 0;
  int v = d;
#pragma unroll
  for (int off = 1; off < 64; off <<= 1) {
    int u = __shfl_up(v, off);
    if (lane >= off) v += u;
  }
  __shared__ int wsum[16];
  if (lane == 63) wsum[wid] = v;
  __syncthreads();
  if (wid == 0) {
    int w = (lane < 16) ? wsum[lane] : 0;
#pragma unroll
    for (int off = 1; off < 16; off <<= 1) {
      int u = __shfl_up(w, off);
      if (lane >= off) w += u;
    }
    if (lane < 16) wsum[lane] = w;
  }
  __syncthreads();
  int incl = v + ((wid > 0) ? wsum[wid - 1] : 0);
  if (i < N_NODES) {
    rs[i] = incl - d;                 // block-local exclusive
    dinv[i] = rsqrtf((float)d);       // deg >= 1 always (self-loop)
  }
  if (tid == 1023) partials[blockIdx.x] = incl;
}

__global__ void scan2_kernel(const int* __restrict__ partials, int* __restrict__ blockoff) {
  int t = threadIdx.x;  // 64 >= SCAN_NBLK
  int own = (t < SCAN_NBLK) ? partials[t] : 0;
  int v = own;
#pragma unroll
  for (int off = 1; off < 64; off <<= 1) {
    int u = __shfl_up(v, off);
    if (t >= off) v += u;
  }
  if (t < SCAN_NBLK) blockoff[t] = v - own;   // exclusive
}

__global__ __launch_bounds__(1024) void scan3_kernel(int* __restrict__ rs,
    int* __restrict__ cur, const int* __restrict__ blockoff) {
  int i = blockIdx.x * 1024 + threadIdx.x;
  if (i >= N_NODES) return;
  int e = rs[i] + blockoff[blockIdx.x];
  rs[i] = e; cur[i] = e;
}

__global__ void fill_kernel(const int* __restrict__ ei, const int* __restrict__ flag,
                            int* __restrict__ cur, int* __restrict__ csr) {
  int e = blockIdx.x * 256 + threadIdx.x;
  if (e >= TOT_E) return;
  int s, d;
  if (e < N_EDGES) {
    if (flag[0]) { s = ei[2 * e]; d = ei[2 * (N_EDGES + e)]; }
    else         { s = ei[e];     d = ei[N_EDGES + e]; }
  } else {
    s = d = e - N_EDGES;  // self-loop
  }
  int pos = atomicAdd(&cur[d], 1);
  csr[pos] = s;
}

__global__ void f2bf_kernel(const float* __restrict__ in, unsigned short* __restrict__ out) {
  long i = (long)(blockIdx.x * 256 + threadIdx.x) * 4;
  if (i >= (long)N_NODES * 128) return;
  float4 v = *(const float4*)(in + i);
  union { unsigned short u[4]; unsigned long long ll; } o;
  o.u[0] = f2bf(v.x); o.u[1] = f2bf(v.y); o.u[2] = f2bf(v.z); o.u[3] = f2bf(v.w);
  *(unsigned long long*)(out + i) = o.ll;
}

// ---- dense matmul: Hb[n][o] = bf16( sum_k Xb[n][k] * W[o][k] ) -----------

template <int OUT>
__global__ __launch_bounds__(256) void mm_kernel(const unsigned short* __restrict__ Xb,
    const float* __restrict__ W, unsigned short* __restrict__ Hb) {
  constexpr int K = 128;
  constexpr int LDW = K + 8;  // pad to break LDS bank aliasing on b128 reads
  __shared__ __align__(16) unsigned short Wl[OUT * LDW];
  int tid = threadIdx.x;
  for (int i = tid; i < OUT * K; i += 256)
    Wl[(i >> 7) * LDW + (i & 127)] = f2bf(W[i]);
  __syncthreads();

  int lane = tid & 63;
  int wv = tid >> 6;
  int m = lane & 15, q = lane >> 4;
  long n0 = (long)blockIdx.x * 64 + wv * 16;
  long arow = n0 + m; if (arow > N_NODES - 1) arow = N_NODES - 1;  // clamp; dead rows discarded
  const unsigned short* xr = Xb + arow * K + q * 8;
  short8 a0 = *(const short8*)(xr);
  short8 a1 = *(const short8*)(xr + 32);
  short8 a2 = *(const short8*)(xr + 64);
  short8 a3 = *(const short8*)(xr + 96);

  f32x4 acc[OUT / 16];
#pragma unroll
  for (int t = 0; t < OUT / 16; t++) acc[t] = (f32x4){0.f, 0.f, 0.f, 0.f};

#pragma unroll
  for (int ot = 0; ot < OUT / 16; ot++) {
    const unsigned short* wrow = Wl + (size_t)(ot * 16 + m) * LDW + q * 8;
    short8 b0 = *(const short8*)(wrow);
    short8 b1 = *(const short8*)(wrow + 32);
    short8 b2 = *(const short8*)(wrow + 64);
    short8 b3 = *(const short8*)(wrow + 96);
    acc[ot] = __builtin_amdgcn_mfma_f32_16x16x32_bf16(a0, b0, acc[ot], 0, 0, 0);
    acc[ot] = __builtin_amdgcn_mfma_f32_16x16x32_bf16(a1, b1, acc[ot], 0, 0, 0);
    acc[ot] = __builtin_amdgcn_mfma_f32_16x16x32_bf16(a2, b2, acc[ot], 0, 0, 0);
    acc[ot] = __builtin_amdgcn_mfma_f32_16x16x32_bf16(a3, b3, acc[ot], 0, 0, 0);
  }

#pragma unroll
  for (int ot = 0; ot < OUT / 16; ot++) {
#pragma unroll
    for (int r = 0; r < 4; r++) {
      long n = n0 + q * 4 + r;            // D: row = quad*4 + reg, col = lane&15
      if (n < N_NODES) Hb[n * OUT + ot * 16 + m] = f2bf(acc[ot][r]);
    }
  }
}

// ---- aggregation: out[i] = dinv[i] * sum_j dinv[s_j] * Hb[s_j] + bias ----
// Hb rows are bf16: 128ch = 64 dwords, 64ch = 32 dwords. Gather dwords.

__global__ __launch_bounds__(256) void agg128_kernel(const unsigned int* __restrict__ H32,
    const int* __restrict__ rs, const int* __restrict__ csr, const float* __restrict__ dinv,
    const float* __restrict__ bias, float* __restrict__ out) {
  int lane = threadIdx.x & 63;                  // dword index in row (2 channels)
  int node = blockIdx.x * 4 + (threadIdx.x >> 6);
  if (node >= N_NODES) return;
  int beg = rs[node], end = rs[node + 1];
  float ax = 0.f, ay = 0.f, bx = 0.f, by = 0.f;
  int j = beg;
  for (; j + 2 <= end; j += 2) {                // 2-edge unroll for load ILP
    int s0 = csr[j], s1 = csr[j + 1];
    float w0 = dinv[s0], w1 = dinv[s1];
    unsigned int v0 = H32[(size_t)s0 * 64 + lane];
    unsigned int v1 = H32[(size_t)s1 * 64 + lane];
    ax += w0 * bf2f(v0 & 0xffffu); ay += w0 * bf2f(v0 >> 16);
    bx += w1 * bf2f(v1 & 0xffffu); by += w1 * bf2f(v1 >> 16);
  }
  if (j < end) {
    int s0 = csr[j];
    float w0 = dinv[s0];
    unsigned int v0 = H32[(size_t)s0 * 64 + lane];
    ax += w0 * bf2f(v0 & 0xffffu); ay += w0 * bf2f(v0 >> 16);
  }
  float di = dinv[node];
  int c = lane * 2;
  out[(size_t)node * 128 + c]     = (ax + bx) * di + bias[c];
  out[(size_t)node * 128 + c + 1] = (ay + by) * di + bias[c + 1];
}

// 64ch: 2 nodes per wave (32 lanes each), lane covers 2 channels (1 dword)
__global__ __launch_bounds__(256) void agg64_kernel(const unsigned int* __restrict__ H32,
    const int* __restrict__ rs, const int* __restrict__ csr, const float* __restrict__ dinv,
    const float* __restrict__ bias, float* __restrict__ out) {
  int l = threadIdx.x & 31;                     // dword index in row
  int node = blockIdx.x * 8 + (threadIdx.x >> 5);
  if (node >= N_NODES) return;
  int beg = rs[node], end = rs[node + 1];
  float ax = 0.f, ay = 0.f, bx = 0.f, by = 0.f;
  int j = beg;
  for (; j + 2 <= end; j += 2) {
    int s0 = csr[j], s1 = csr[j + 1];
    float w0 = dinv[s0], w1 = dinv[s1];
    unsigned int v0 = H32[(size_t)s0 * 32 + l];
    unsigned int v1 = H32[(size_t)s1 * 32 + l];
    ax += w0 * bf2f(v0 & 0xffffu); ay += w0 * bf2f(v0 >> 16);
    bx += w1 * bf2f(v1 & 0xffffu); by += w1 * bf2f(v1 >> 16);
  }
  if (j < end) {
    int s0 = csr[j];
    float w0 = dinv[s0];
    unsigned int v0 = H32[(size_t)s0 * 32 + l];
    ax += w0 * bf2f(v0 & 0xffffu); ay += w0 * bf2f(v0 >> 16);
  }
  float di = dinv[node];
  int c = l * 2;
  out[(size_t)node * 64 + c]     = (ax + bx) * di + bias[c];
  out[(size_t)node * 64 + c + 1] = (ay + by) * di + bias[c + 1];
}

// ---- BN stats + fused BN/ReLU/bf16-cast ----------------------------------

__global__ __launch_bounds__(128) void stats_kernel(const float* __restrict__ H,
                                                    float* __restrict__ sums) {
  int c = threadIdx.x;  // 128
  float s = 0.f, s2 = 0.f;
  for (int r = blockIdx.x; r < N_NODES; r += gridDim.x) {
    float v = H[(size_t)r * 128 + c];
    s += v; s2 += v * v;
  }
  atomicAdd(&sums[c], s);
  atomicAdd(&sums[128 + c], s2);
}

__global__ void bnrelu_kernel(const float* __restrict__ H, const float* __restrict__ sums,
    const float* __restrict__ g, const float* __restrict__ bt,
    unsigned short* __restrict__ Xb) {
  long i = (long)(blockIdx.x * 256 + threadIdx.x) * 4;
  if (i >= (long)N_NODES * 128) return;
  int c = (int)(i & 127);
  float4 v = *(const float4*)(H + i);
  float vv[4] = {v.x, v.y, v.z, v.w};
  const float inv_n = 1.0f / (float)N_NODES;
  union { unsigned short u[4]; unsigned long long ll; } o;
#pragma unroll
  for (int t = 0; t < 4; t++) {
    int ch = c + t;
    float mean = sums[ch] * inv_n;
    float var  = sums[128 + ch] * inv_n - mean * mean;
    float sc = g[ch] * rsqrtf(var + 1e-5f);
    float sh = bt[ch] - mean * sc;
    float r = vv[t] * sc + sh;
    r = r > 0.f ? r : 0.f;
    o.u[t] = f2bf(r);
  }
  *(unsigned long long*)(Xb + i) = o.ll;
}

// ---- driver --------------------------------------------------------------

extern "C" void kernel_launch(void* const* d_in, const int* in_sizes, int n_in,
                              void* d_out, int out_size, void* d_ws, size_t ws_size,
                              hipStream_t stream) {
  const float* x   = (const float*)d_in[0];
  const int*   ei  = (const int*)d_in[1];
  const float* W1  = (const float*)d_in[2];
  const float* b1  = (const float*)d_in[3];
  const float* W2  = (const float*)d_in[4];
  const float* b2  = (const float*)d_in[5];
  const float* W3  = (const float*)d_in[6];
  const float* b3  = (const float*)d_in[7];
  const float* g1  = (const float*)d_in[8];
  const float* bt1 = (const float*)d_in[9];
  const float* g2  = (const float*)d_in[10];
  const float* bt2 = (const float*)d_in[11];
  float* out = (float*)d_out;

  char* p = (char*)d_ws;
  auto carve = [&](size_t bytes) { char* r = p; p += (bytes + 255) & ~(size_t)255; return r; };
  int*   deg   = (int*)  carve((size_t)N_NODES * 4);
  int*   rs    = (int*)  carve((size_t)(N_NODES + 1) * 4);
  int*   cur   = (int*)  carve((size_t)N_NODES * 4);
  float* dinv  = (float*)carve((size_t)N_NODES * 4);
  int*   csr   = (int*)  carve((size_t)TOT_E * 4);
  float* sums1 = (float*)carve(256 * 4);
  float* sums2 = (float*)carve(256 * 4);
  int*   flag  = (int*)  carve(256);
  int*   partials = (int*)carve(64 * 4);
  int*   blockoff = (int*)carve(64 * 4);
  unsigned short* Xb = (unsigned short*)carve((size_t)N_NODES * 128 * 2);
  unsigned short* Hb = (unsigned short*)carve((size_t)N_NODES * 128 * 2);
  float* bufB  = (float*)carve((size_t)N_NODES * 128 * 4);

  const int EW_BLOCKS = (N_NODES * 128 / 4 + 255) / 256;  // 6250

  init_kernel<<<(N_NODES + 255) / 256, 256, 0, stream>>>(deg, sums1, sums2, rs);
  detect_kernel<<<1, 64, 0, stream>>>(ei, flag);
  count_kernel<<<(N_EDGES + 255) / 256, 256, 0, stream>>>(ei, flag, deg);
  scan1_kernel<<<SCAN_NBLK, 1024, 0, stream>>>(deg, rs, dinv, partials);
  scan2_kernel<<<1, 64, 0, stream>>>(partials, blockoff);
  scan3_kernel<<<SCAN_NBLK, 1024, 0, stream>>>(rs, cur, blockoff);
  fill_kernel<<<(TOT_E + 255) / 256, 256, 0, stream>>>(ei, flag, cur, csr);
  f2bf_kernel<<<EW_BLOCKS, 256, 0, stream>>>(x, Xb);

  // layer 1
  mm_kernel<128><<<(N_NODES + 63) / 64, 256, 0, stream>>>(Xb, W1, Hb);
  agg128_kernel<<<(N_NODES + 3) / 4, 256, 0, stream>>>((const unsigned int*)Hb, rs, csr, dinv, b1, bufB);
  stats_kernel<<<512, 128, 0, stream>>>(bufB, sums1);
  bnrelu_kernel<<<EW_BLOCKS, 256, 0, stream>>>(bufB, sums1, g1, bt1, Xb);

  // layer 2
  mm_kernel<128><<<(N_NODES + 63) / 64, 256, 0, stream>>>(Xb, W2, Hb);
  agg128_kernel<<<(N_NODES + 3) / 4, 256, 0, stream>>>((const unsigned int*)Hb, rs, csr, dinv, b2, bufB);
  stats_kernel<<<512, 128, 0, stream>>>(bufB, sums2);
  bnrelu_kernel<<<EW_BLOCKS, 256, 0, stream>>>(bufB, sums2, g2, bt2, Xb);

  // layer 3 (128 -> 64), aggregate straight into d_out
  mm_kernel<64><<<(N_NODES + 63) / 64, 256, 0, stream>>>(Xb, W3, Hb);
  agg64_kernel<<<(N_NODES + 7) / 8, 256, 0, stream>>>((const unsigned int*)Hb, rs, csr, dinv, b3, out);
}

// Round 3
// 389.421 us; speedup vs baseline: 1.4527x; 1.1636x over previous
//
#include <hip/hip_runtime.h>
#include <hip/hip_bf16.h>

#define N_NODES 50000
#define N_EDGES 800000
#define TOT_E   (N_EDGES + N_NODES)
#define SCAN_NBLK ((N_NODES + 1023) / 1024)   // 49

typedef __attribute__((ext_vector_type(8))) short short8;
typedef __attribute__((ext_vector_type(4))) float f32x4;

__device__ __forceinline__ unsigned short f2bf(float f) {
  union { float f; unsigned int u; } x; x.f = f;
  unsigned int u = x.u;
  unsigned int r = (u + 0x7FFFu + ((u >> 16) & 1u)) >> 16;  // RNE
  return (unsigned short)r;
}
__device__ __forceinline__ float bf2f(unsigned int u16) {
  union { unsigned int u; float f; } x; x.u = u16 << 16; return x.f;
}

// ---- setup: zero sums, deg=1 (self-loop), rs[N], dtype-detect flag -------

__global__ void init_kernel(int* __restrict__ deg, float* __restrict__ sums1,
                            float* __restrict__ sums2, int* __restrict__ rs,
                            const int* __restrict__ ei, int* __restrict__ flag) {
  int i = blockIdx.x * 256 + threadIdx.x;
  if (i < N_NODES) deg[i] = 1;
  if (i < 256) { sums1[i] = 0.f; sums2[i] = 0.f; }
  if (i == 0) rs[N_NODES] = TOT_E;
  // int64 detection: odd int32 words of first 64 entries all zero => int64
  if (blockIdx.x == 0 && threadIdx.x < 64) {
    int v = ei[2 * threadIdx.x + 1];
    unsigned long long b = __ballot(v != 0);
    if (threadIdx.x == 0) flag[0] = (b == 0ULL) ? 1 : 0;
  }
}

__global__ void count_kernel(const int* __restrict__ ei, const int* __restrict__ flag,
                             int* __restrict__ deg) {
  int e0 = (blockIdx.x * 256 + threadIdx.x) * 2;
  if (e0 >= N_EDGES) return;
  int d0, d1;
  if (flag[0]) {
    int4 v = *(const int4*)(ei + 2 * (N_EDGES + e0));
    d0 = v.x; d1 = v.z;
  } else {
    int2 v = *(const int2*)(ei + N_EDGES + e0);
    d0 = v.x; d1 = v.y;
  }
  atomicAdd(&deg[d0], 1);
  if (e0 + 1 < N_EDGES) atomicAdd(&deg[d1], 1);
}

// ---- parallel exclusive scan of deg -> rs/cur, plus dinv -----------------

__global__ __launch_bounds__(1024) void scan1_kernel(const int* __restrict__ deg,
    int* __restrict__ rs, float* __restrict__ dinv, int* __restrict__ partials) {
  int tid = threadIdx.x;
  int lane = tid & 63, wid = tid >> 6;   // 16 waves
  int i = blockIdx.x * 1024 + tid;
  int d = (i < N_NODES) ? deg[i] : 0;
  int v = d;
#pragma unroll
  for (int off = 1; off < 64; off <<= 1) {
    int u = __shfl_up(v, off);
    if (lane >= off) v += u;
  }
  __shared__ int wsum[16];
  if (lane == 63) wsum[wid] = v;
  __syncthreads();
  if (wid == 0) {
    int w = (lane < 16) ? wsum[lane] : 0;
#pragma unroll
    for (int off = 1; off < 16; off <<= 1) {
      int u = __shfl_up(w, off);
      if (lane >= off) w += u;
    }
    if (lane < 16) wsum[lane] = w;
  }
  __syncthreads();
  int incl = v + ((wid > 0) ? wsum[wid - 1] : 0);
  if (i < N_NODES) {
    rs[i] = incl - d;                 // block-local exclusive
    dinv[i] = rsqrtf((float)d);       // deg >= 1 always
  }
  if (tid == 1023) partials[blockIdx.x] = incl;
}

// scan2 folded in: each block reduces partials[0..blockIdx-1] itself
__global__ __launch_bounds__(1024) void scan3_kernel(int* __restrict__ rs,
    int* __restrict__ cur, const int* __restrict__ partials) {
  __shared__ int boff;
  int tid = threadIdx.x;
  if (tid < 64) {
    int v = (tid < blockIdx.x) ? partials[tid] : 0;  // blockIdx <= 49 <= 64
#pragma unroll
    for (int off = 32; off; off >>= 1) v += __shfl_xor(v, off);
    if (tid == 0) boff = v;
  }
  __syncthreads();
  int i = blockIdx.x * 1024 + tid;
  if (i < N_NODES) {
    int e = rs[i] + boff;
    rs[i] = e; cur[i] = e;
  }
}

__global__ void fill_kernel(const int* __restrict__ ei, const int* __restrict__ flag,
                            int* __restrict__ cur, int* __restrict__ csr) {
  int e0 = (blockIdx.x * 256 + threadIdx.x) * 2;
  if (e0 >= TOT_E) return;
  int s0, d0, s1, d1;
  bool two = (e0 + 1 < TOT_E);
  if (e0 + 1 < N_EDGES) {               // both real edges
    if (flag[0]) {
      int4 sv = *(const int4*)(ei + 2 * e0);
      int4 dv = *(const int4*)(ei + 2 * (N_EDGES + e0));
      s0 = sv.x; s1 = sv.z; d0 = dv.x; d1 = dv.z;
    } else {
      int2 sv = *(const int2*)(ei + e0);
      int2 dv = *(const int2*)(ei + N_EDGES + e0);
      s0 = sv.x; s1 = sv.y; d0 = dv.x; d1 = dv.y;
    }
  } else {
    auto one = [&](int e, int& s, int& d) {
      if (e < N_EDGES) {
        if (flag[0]) { s = ei[2 * e]; d = ei[2 * (N_EDGES + e)]; }
        else         { s = ei[e];     d = ei[N_EDGES + e]; }
      } else { s = d = e - N_EDGES; }
    };
    one(e0, s0, d0);
    if (two) one(e0 + 1, s1, d1);
  }
  int p0 = atomicAdd(&cur[d0], 1);
  csr[p0] = s0;
  if (two) { int p1 = atomicAdd(&cur[d1], 1); csr[p1] = s1; }
}

// ---- dense matmul with fused A-side BN/ReLU/bf16 cast --------------------
// BN==0: A is fp32 [N][128] raw (layer 1 input x).
// BN==1: A is bf16-packed dwords [N][64] (prev agg out); apply BN+ReLU.
// Hb[n][o] = bf16( sum_k a(n,k) * W[o][k] )

template <int OUT, int BN>
__global__ __launch_bounds__(256) void mm_kernel(const void* __restrict__ Ain,
    const float* __restrict__ sums, const float* __restrict__ g,
    const float* __restrict__ bt, const float* __restrict__ W,
    unsigned short* __restrict__ Hb) {
  constexpr int K = 128;
  constexpr int LDW = K + 8;  // pad to break LDS bank aliasing on b128 reads
  __shared__ __align__(16) unsigned short Wl[OUT * LDW];
  __shared__ float scs[128], shs[128];
  int tid = threadIdx.x;
  for (int i = tid; i < OUT * K; i += 256)
    Wl[(i >> 7) * LDW + (i & 127)] = f2bf(W[i]);
  if (BN && tid < 128) {
    const float inv_n = 1.0f / (float)N_NODES;
    float mean = sums[tid] * inv_n;
    float var  = sums[128 + tid] * inv_n - mean * mean;
    float sc = g[tid] * rsqrtf(var + 1e-5f);
    scs[tid] = sc;
    shs[tid] = bt[tid] - mean * sc;
  }
  __syncthreads();

  int lane = tid & 63;
  int wv = tid >> 6;
  int m = lane & 15, q = lane >> 4;
  long n0 = (long)blockIdx.x * 64 + wv * 16;
  long arow = n0 + m; if (arow > N_NODES - 1) arow = N_NODES - 1;  // clamp

  short8 a[4];
  if (BN) {
    const unsigned int* A32 = (const unsigned int*)Ain;
#pragma unroll
    for (int kb = 0; kb < 4; kb++) {
      uint4 v = *(const uint4*)(A32 + (size_t)arow * 64 + kb * 16 + q * 4);
      unsigned int vv[4] = {v.x, v.y, v.z, v.w};
      short8 t;
#pragma unroll
      for (int j = 0; j < 4; j++) {
        int ch = kb * 32 + q * 8 + j * 2;
        float lo = bf2f(vv[j] & 0xffffu) * scs[ch] + shs[ch];
        float hi = bf2f(vv[j] >> 16) * scs[ch + 1] + shs[ch + 1];
        lo = fmaxf(lo, 0.f); hi = fmaxf(hi, 0.f);
        t[2 * j] = (short)f2bf(lo); t[2 * j + 1] = (short)f2bf(hi);
      }
      a[kb] = t;
    }
  } else {
    const float* Af = (const float*)Ain;
#pragma unroll
    for (int kb = 0; kb < 4; kb++) {
      const float* p = Af + (size_t)arow * 128 + kb * 32 + q * 8;
      float4 v0 = *(const float4*)(p);
      float4 v1 = *(const float4*)(p + 4);
      short8 t;
      t[0] = (short)f2bf(v0.x); t[1] = (short)f2bf(v0.y);
      t[2] = (short)f2bf(v0.z); t[3] = (short)f2bf(v0.w);
      t[4] = (short)f2bf(v1.x); t[5] = (short)f2bf(v1.y);
      t[6] = (short)f2bf(v1.z); t[7] = (short)f2bf(v1.w);
      a[kb] = t;
    }
  }

  f32x4 acc[OUT / 16];
#pragma unroll
  for (int t = 0; t < OUT / 16; t++) acc[t] = (f32x4){0.f, 0.f, 0.f, 0.f};

#pragma unroll
  for (int ot = 0; ot < OUT / 16; ot++) {
    const unsigned short* wrow = Wl + (size_t)(ot * 16 + m) * LDW + q * 8;
    short8 b0 = *(const short8*)(wrow);
    short8 b1 = *(const short8*)(wrow + 32);
    short8 b2 = *(const short8*)(wrow + 64);
    short8 b3 = *(const short8*)(wrow + 96);
    acc[ot] = __builtin_amdgcn_mfma_f32_16x16x32_bf16(a[0], b0, acc[ot], 0, 0, 0);
    acc[ot] = __builtin_amdgcn_mfma_f32_16x16x32_bf16(a[1], b1, acc[ot], 0, 0, 0);
    acc[ot] = __builtin_amdgcn_mfma_f32_16x16x32_bf16(a[2], b2, acc[ot], 0, 0, 0);
    acc[ot] = __builtin_amdgcn_mfma_f32_16x16x32_bf16(a[3], b3, acc[ot], 0, 0, 0);
  }

#pragma unroll
  for (int ot = 0; ot < OUT / 16; ot++) {
#pragma unroll
    for (int r = 0; r < 4; r++) {
      long n = n0 + q * 4 + r;            // D: row = quad*4 + reg, col = lane&15
      if (n < N_NODES) Hb[n * OUT + ot * 16 + m] = f2bf(acc[ot][r]);
    }
  }
}

// ---- aggregation: out[i] = dinv[i] * sum_j dinv[s_j] * Hb[s_j] + bias ----
// 4-edge unroll for load ILP (latency-bound gather). Output bf16-packed.

__global__ __launch_bounds__(256) void agg128_kernel(const unsigned int* __restrict__ H32,
    const int* __restrict__ rs, const int* __restrict__ csr, const float* __restrict__ dinv,
    const float* __restrict__ bias, unsigned int* __restrict__ outb) {
  int lane = threadIdx.x & 63;                  // dword index in row (2 channels)
  int node = blockIdx.x * 4 + (threadIdx.x >> 6);
  if (node >= N_NODES) return;
  int beg = rs[node], end = rs[node + 1];
  float a0x = 0.f, a0y = 0.f, a1x = 0.f, a1y = 0.f;
  float a2x = 0.f, a2y = 0.f, a3x = 0.f, a3y = 0.f;
  int j = beg;
  for (; j + 4 <= end; j += 4) {
    int s0 = csr[j], s1 = csr[j + 1], s2 = csr[j + 2], s3 = csr[j + 3];
    float w0 = dinv[s0], w1 = dinv[s1], w2 = dinv[s2], w3 = dinv[s3];
    unsigned int v0 = H32[(size_t)s0 * 64 + lane];
    unsigned int v1 = H32[(size_t)s1 * 64 + lane];
    unsigned int v2 = H32[(size_t)s2 * 64 + lane];
    unsigned int v3 = H32[(size_t)s3 * 64 + lane];
    a0x += w0 * bf2f(v0 & 0xffffu); a0y += w0 * bf2f(v0 >> 16);
    a1x += w1 * bf2f(v1 & 0xffffu); a1y += w1 * bf2f(v1 >> 16);
    a2x += w2 * bf2f(v2 & 0xffffu); a2y += w2 * bf2f(v2 >> 16);
    a3x += w3 * bf2f(v3 & 0xffffu); a3y += w3 * bf2f(v3 >> 16);
  }
  for (; j < end; ++j) {
    int s0 = csr[j];
    float w0 = dinv[s0];
    unsigned int v0 = H32[(size_t)s0 * 64 + lane];
    a0x += w0 * bf2f(v0 & 0xffffu); a0y += w0 * bf2f(v0 >> 16);
  }
  float di = dinv[node];
  int c = lane * 2;
  float rx = (a0x + a1x + a2x + a3x) * di + bias[c];
  float ry = (a0y + a1y + a2y + a3y) * di + bias[c + 1];
  outb[(size_t)node * 64 + lane] = (unsigned int)f2bf(rx) | ((unsigned int)f2bf(ry) << 16);
}

// 64ch final layer: 2 nodes per wave (32 lanes each), fp32 output to d_out
__global__ __launch_bounds__(256) void agg64_kernel(const unsigned int* __restrict__ H32,
    const int* __restrict__ rs, const int* __restrict__ csr, const float* __restrict__ dinv,
    const float* __restrict__ bias, float* __restrict__ out) {
  int l = threadIdx.x & 31;                     // dword index in row
  int node = blockIdx.x * 8 + (threadIdx.x >> 5);
  if (node >= N_NODES) return;
  int beg = rs[node], end = rs[node + 1];
  float a0x = 0.f, a0y = 0.f, a1x = 0.f, a1y = 0.f;
  float a2x = 0.f, a2y = 0.f, a3x = 0.f, a3y = 0.f;
  int j = beg;
  for (; j + 4 <= end; j += 4) {
    int s0 = csr[j], s1 = csr[j + 1], s2 = csr[j + 2], s3 = csr[j + 3];
    float w0 = dinv[s0], w1 = dinv[s1], w2 = dinv[s2], w3 = dinv[s3];
    unsigned int v0 = H32[(size_t)s0 * 32 + l];
    unsigned int v1 = H32[(size_t)s1 * 32 + l];
    unsigned int v2 = H32[(size_t)s2 * 32 + l];
    unsigned int v3 = H32[(size_t)s3 * 32 + l];
    a0x += w0 * bf2f(v0 & 0xffffu); a0y += w0 * bf2f(v0 >> 16);
    a1x += w1 * bf2f(v1 & 0xffffu); a1y += w1 * bf2f(v1 >> 16);
    a2x += w2 * bf2f(v2 & 0xffffu); a2y += w2 * bf2f(v2 >> 16);
    a3x += w3 * bf2f(v3 & 0xffffu); a3y += w3 * bf2f(v3 >> 16);
  }
  for (; j < end; ++j) {
    int s0 = csr[j];
    float w0 = dinv[s0];
    unsigned int v0 = H32[(size_t)s0 * 32 + l];
    a0x += w0 * bf2f(v0 & 0xffffu); a0y += w0 * bf2f(v0 >> 16);
  }
  float di = dinv[node];
  int c = l * 2;
  out[(size_t)node * 64 + c]     = (a0x + a1x + a2x + a3x) * di + bias[c];
  out[(size_t)node * 64 + c + 1] = (a0y + a1y + a2y + a3y) * di + bias[c + 1];
}

// ---- BN stats over bf16-packed agg output --------------------------------

__global__ __launch_bounds__(256) void stats_kernel(const unsigned int* __restrict__ B32,
                                                    float* __restrict__ sums) {
  __shared__ float lsx[256], lsy[256], l2x[256], l2y[256];
  int tid = threadIdx.x;
  int d = tid & 63, grp = tid >> 6;
  float sx = 0.f, sy = 0.f, qx = 0.f, qy = 0.f;
  for (int r = blockIdx.x * 4 + grp; r < N_NODES; r += gridDim.x * 4) {
    unsigned int v = B32[(size_t)r * 64 + d];
    float x = bf2f(v & 0xffffu), y = bf2f(v >> 16);
    sx += x; sy += y; qx += x * x; qy += y * y;
  }
  lsx[tid] = sx; lsy[tid] = sy; l2x[tid] = qx; l2y[tid] = qy;
  __syncthreads();
  if (tid < 64) {
    float ax = lsx[tid] + lsx[64 + tid] + lsx[128 + tid] + lsx[192 + tid];
    float ay = lsy[tid] + lsy[64 + tid] + lsy[128 + tid] + lsy[192 + tid];
    float bx = l2x[tid] + l2x[64 + tid] + l2x[128 + tid] + l2x[192 + tid];
    float by = l2y[tid] + l2y[64 + tid] + l2y[128 + tid] + l2y[192 + tid];
    atomicAdd(&sums[2 * tid], ax);
    atomicAdd(&sums[2 * tid + 1], ay);
    atomicAdd(&sums[128 + 2 * tid], bx);
    atomicAdd(&sums[128 + 2 * tid + 1], by);
  }
}

// ---- driver --------------------------------------------------------------

extern "C" void kernel_launch(void* const* d_in, const int* in_sizes, int n_in,
                              void* d_out, int out_size, void* d_ws, size_t ws_size,
                              hipStream_t stream) {
  const float* x   = (const float*)d_in[0];
  const int*   ei  = (const int*)d_in[1];
  const float* W1  = (const float*)d_in[2];
  const float* b1  = (const float*)d_in[3];
  const float* W2  = (const float*)d_in[4];
  const float* b2  = (const float*)d_in[5];
  const float* W3  = (const float*)d_in[6];
  const float* b3  = (const float*)d_in[7];
  const float* g1  = (const float*)d_in[8];
  const float* bt1 = (const float*)d_in[9];
  const float* g2  = (const float*)d_in[10];
  const float* bt2 = (const float*)d_in[11];
  float* out = (float*)d_out;

  char* p = (char*)d_ws;
  auto carve = [&](size_t bytes) { char* r = p; p += (bytes + 255) & ~(size_t)255; return r; };
  int*   deg   = (int*)  carve((size_t)N_NODES * 4);
  int*   rs    = (int*)  carve((size_t)(N_NODES + 1) * 4);
  int*   cur   = (int*)  carve((size_t)N_NODES * 4);
  float* dinv  = (float*)carve((size_t)N_NODES * 4);
  int*   csr   = (int*)  carve((size_t)TOT_E * 4);
  float* sums1 = (float*)carve(256 * 4);
  float* sums2 = (float*)carve(256 * 4);
  int*   flag  = (int*)  carve(256);
  int*   partials = (int*)carve(64 * 4);
  unsigned short* Hb = (unsigned short*)carve((size_t)N_NODES * 128 * 2);
  unsigned int*   Bb = (unsigned int*)  carve((size_t)N_NODES * 64 * 4);

  init_kernel<<<(N_NODES + 255) / 256, 256, 0, stream>>>(deg, sums1, sums2, rs, ei, flag);
  count_kernel<<<(N_EDGES / 2 + 255) / 256, 256, 0, stream>>>(ei, flag, deg);
  scan1_kernel<<<SCAN_NBLK, 1024, 0, stream>>>(deg, rs, dinv, partials);
  scan3_kernel<<<SCAN_NBLK, 1024, 0, stream>>>(rs, cur, partials);
  fill_kernel<<<(TOT_E / 2 + 255) / 256, 256, 0, stream>>>(ei, flag, cur, csr);

  // layer 1: mm(x) -> agg -> stats
  mm_kernel<128, 0><<<(N_NODES + 63) / 64, 256, 0, stream>>>(x, sums1, g1, bt1, W1, Hb);
  agg128_kernel<<<(N_NODES + 3) / 4, 256, 0, stream>>>((const unsigned int*)Hb, rs, csr, dinv, b1, Bb);
  stats_kernel<<<512, 256, 0, stream>>>(Bb, sums1);

  // layer 2: mm(BN1(Bb)) -> agg -> stats
  mm_kernel<128, 1><<<(N_NODES + 63) / 64, 256, 0, stream>>>(Bb, sums1, g1, bt1, W2, Hb);
  agg128_kernel<<<(N_NODES + 3) / 4, 256, 0, stream>>>((const unsigned int*)Hb, rs, csr, dinv, b2, Bb);
  stats_kernel<<<512, 256, 0, stream>>>(Bb, sums2);

  // layer 3: mm(BN2(Bb)) -> agg -> out (fp32)
  mm_kernel<64, 1><<<(N_NODES + 63) / 64, 256, 0, stream>>>(Bb, sums2, g2, bt2, W3, Hb);
  agg64_kernel<<<(N_NODES + 7) / 8, 256, 0, stream>>>((const unsigned int*)Hb, rs, csr, dinv, b3, out);
}

// Round 4
// 352.719 us; speedup vs baseline: 1.6039x; 1.1041x over previous
//
#include <hip/hip_runtime.h>
#include <hip/hip_bf16.h>

#define N_NODES 50000
#define N_EDGES 800000
#define TOT_E   (N_EDGES + N_NODES)
#define NBUCK   ((N_NODES + 127) / 128)     // 391 buckets of 128 dst nodes
#define BCAP    3072                         // bucket capacity (avg 2048, max ~2300)
#define PART_BLOCKS 64
#define EPB     (N_EDGES / PART_BLOCKS)      // 12500 edges per partition block

typedef __attribute__((ext_vector_type(8))) short short8;
typedef __attribute__((ext_vector_type(4))) float f32x4;

__device__ __forceinline__ unsigned short f2bf(float f) {
  union { float f; unsigned int u; } x; x.f = f;
  unsigned int u = x.u;
  unsigned int r = (u + 0x7FFFu + ((u >> 16) & 1u)) >> 16;  // RNE
  return (unsigned short)r;
}
__device__ __forceinline__ float bf2f(unsigned int u16) {
  union { unsigned int u; float f; } x; x.u = u16 << 16; return x.f;
}

// ---- init: zero sums, bucket cursors, rs[N], dtype-detect flag -----------

__global__ void init_kernel(float* __restrict__ sums1, float* __restrict__ sums2,
                            int* __restrict__ rs, int* __restrict__ cur,
                            const int* __restrict__ ei, int* __restrict__ flag) {
  int i = blockIdx.x * 256 + threadIdx.x;
  if (i < 256) { sums1[i] = 0.f; sums2[i] = 0.f; }
  if (i < NBUCK) cur[i] = i * BCAP;
  if (i == 0) rs[N_NODES] = TOT_E;
  // int64 detection: odd int32 words of first 64 entries all zero => int64
  if (blockIdx.x == 0 && threadIdx.x < 64) {
    int v = ei[2 * threadIdx.x + 1];
    unsigned long long b = __ballot(v != 0);
    if (threadIdx.x == 0) flag[0] = (b == 0ULL) ? 1 : 0;
  }
}

// ---- partition: bucket edges by dst>>7, LDS-sorted coalesced flush -------

__global__ __launch_bounds__(1024) void part_kernel(const int* __restrict__ ei,
    const int* __restrict__ flag, int* __restrict__ cur, unsigned int* __restrict__ part) {
  __shared__ int hist[NBUCK];
  __shared__ int hist2[NBUCK];
  __shared__ int lexcl[NBUCK];
  __shared__ int gbase[NBUCK];
  __shared__ int wtot[8];
  __shared__ unsigned int sorted[EPB];
  int tid = threadIdx.x;
  int e0 = blockIdx.x * EPB;
  for (int i = tid; i < NBUCK; i += 1024) { hist[i] = 0; hist2[i] = 0; }
  __syncthreads();
  bool i64 = flag[0] != 0;
  // pass 1: bucket histogram
  for (int i = tid; i < EPB; i += 1024) {
    int e = e0 + i;
    int d = i64 ? ei[2 * (N_EDGES + e)] : ei[N_EDGES + e];
    atomicAdd(&hist[d >> 7], 1);
  }
  __syncthreads();
  // exclusive scan of hist -> lexcl (NBUCK <= 512: 8 waves)
  if (tid < 512) {
    int lane = tid & 63, w = tid >> 6;
    int h = (tid < NBUCK) ? hist[tid] : 0;
    int v = h;
#pragma unroll
    for (int off = 1; off < 64; off <<= 1) {
      int u = __shfl_up(v, off);
      if (lane >= off) v += u;
    }
    if (lane == 63) wtot[w] = v;
    if (tid < NBUCK) lexcl[tid] = v - h;
  }
  __syncthreads();
  if (tid < NBUCK) {
    int w = tid >> 6, off = 0;
    for (int k = 0; k < w; k++) off += wtot[k];
    lexcl[tid] += off;
    gbase[tid] = atomicAdd(&cur[tid], hist[tid]);   // reserve global range
  }
  __syncthreads();
  // pass 2: stage edges sorted by bucket in LDS
  for (int i = tid; i < EPB; i += 1024) {
    int e = e0 + i;
    int s, d;
    if (i64) { s = ei[2 * e]; d = ei[2 * (N_EDGES + e)]; }
    else     { s = ei[e];     d = ei[N_EDGES + e]; }
    int b = d >> 7;
    int ls = atomicAdd(&hist2[b], 1);
    sorted[lexcl[b] + ls] = ((unsigned int)d << 16) | (unsigned int)s;
  }
  __syncthreads();
  // flush: consecutive tid -> consecutive slots within bucket (coalesced runs)
  for (int j = tid; j < EPB; j += 1024) {
    unsigned int pk = sorted[j];
    int b = (int)(pk >> 23);                      // (d>>16)>>7
    part[gbase[b] + (j - lexcl[b])] = pk;
  }
}

// ---- bscan: csrbase[b] = sum of real counts of buckets < b + self-loops --

__global__ __launch_bounds__(512) void bscan_kernel(const int* __restrict__ cur,
                                                    int* __restrict__ csrbase) {
  __shared__ int wtot[8];
  int tid = threadIdx.x;
  int lane = tid & 63, w = tid >> 6;
  int r = (tid < NBUCK) ? (cur[tid] - tid * BCAP) : 0;
  int v = r;
#pragma unroll
  for (int off = 1; off < 64; off <<= 1) {
    int u = __shfl_up(v, off);
    if (lane >= off) v += u;
  }
  if (lane == 63) wtot[w] = v;
  __syncthreads();
  if (tid < NBUCK) {
    int off = 0;
    for (int k = 0; k < w; k++) off += wtot[k];
    csrbase[tid] = v - r + off + tid * 128;       // +128 self-loops per prior bucket
  }
}

// ---- finalize: per-bucket CSR (ushort), rs, dinv; neighbor src-sort ------

__global__ __launch_bounds__(256) void fin_kernel(const unsigned int* __restrict__ part,
    const int* __restrict__ cur, const int* __restrict__ csrbase,
    unsigned short* __restrict__ csr, int* __restrict__ rs, float* __restrict__ dinv) {
  __shared__ int cnt[128], excl[128], iscan[128];
  __shared__ unsigned short ord[BCAP];
  __shared__ unsigned short cls[BCAP + 128];
  int b = blockIdx.x, tid = threadIdx.x;
  int n0 = b * 128;
  int nn = N_NODES - n0; if (nn > 128) nn = 128;
  int ecnt = cur[b] - b * BCAP; if (ecnt > BCAP) ecnt = BCAP;
  int ebase = b * BCAP;
  if (tid < 128) cnt[tid] = 1;                    // self-loop
  __syncthreads();
  for (int i = tid; i < ecnt; i += 256) {
    int dl = (int)((part[ebase + i] >> 16) & 127u);
    ord[i] = (unsigned short)atomicAdd(&cnt[dl], 1);
  }
  __syncthreads();
  // exclusive scan of cnt[0..128): 2 waves
  if (tid < 128) {
    int lane = tid & 63;
    int c = cnt[tid], v = c;
#pragma unroll
    for (int off = 1; off < 64; off <<= 1) {
      int u = __shfl_up(v, off);
      if (lane >= off) v += u;
    }
    iscan[tid] = v;
  }
  __syncthreads();
  if (tid < 128)
    excl[tid] = iscan[tid] - cnt[tid] + ((tid >= 64) ? iscan[63] : 0);
  __syncthreads();
  // place self-loops then edges
  if (tid < nn) cls[excl[tid]] = (unsigned short)(n0 + tid);
  __syncthreads();
  for (int i = tid; i < ecnt; i += 256) {
    unsigned int pk = part[ebase + i];
    int dl = (int)((pk >> 16) & 127u);
    cls[excl[dl] + ord[i]] = (unsigned short)(pk & 0xffffu);
  }
  __syncthreads();
  // per-node insertion sort by src (DRAM-row locality for gathers)
  if (tid < nn) {
    int lo = excl[tid], hi = excl[tid] + cnt[tid];
    for (int i2 = lo + 1; i2 < hi; i2++) {
      unsigned short v = cls[i2]; int j2 = i2 - 1;
      while (j2 >= lo && cls[j2] > v) { cls[j2 + 1] = cls[j2]; j2--; }
      cls[j2 + 1] = v;
    }
  }
  __syncthreads();
  int base = csrbase[b];
  int tot = ecnt + nn;
  for (int j = tid; j < tot; j += 256) csr[base + j] = cls[j];
  if (tid < nn) {
    rs[n0 + tid] = base + excl[tid];
    dinv[n0 + tid] = rsqrtf((float)cnt[tid]);
  }
}

// ---- dense matmul with fused A-side BN/ReLU/bf16 cast --------------------
// BN==0: A is fp32 [N][128] raw (layer 1 input x).
// BN==1: A is bf16-packed dwords [N][64] (prev agg out); apply BN+ReLU.

template <int OUT, int BN>
__global__ __launch_bounds__(256) void mm_kernel(const void* __restrict__ Ain,
    const float* __restrict__ sums, const float* __restrict__ g,
    const float* __restrict__ bt, const float* __restrict__ W,
    unsigned short* __restrict__ Hb) {
  constexpr int K = 128;
  constexpr int LDW = K + 8;
  __shared__ __align__(16) unsigned short Wl[OUT * LDW];
  __shared__ float scs[128], shs[128];
  int tid = threadIdx.x;
  for (int i = tid; i < OUT * K; i += 256)
    Wl[(i >> 7) * LDW + (i & 127)] = f2bf(W[i]);
  if (BN && tid < 128) {
    const float inv_n = 1.0f / (float)N_NODES;
    float mean = sums[tid] * inv_n;
    float var  = sums[128 + tid] * inv_n - mean * mean;
    float sc = g[tid] * rsqrtf(var + 1e-5f);
    scs[tid] = sc;
    shs[tid] = bt[tid] - mean * sc;
  }
  __syncthreads();

  int lane = tid & 63;
  int wv = tid >> 6;
  int m = lane & 15, q = lane >> 4;
  long n0 = (long)blockIdx.x * 64 + wv * 16;
  long arow = n0 + m; if (arow > N_NODES - 1) arow = N_NODES - 1;

  short8 a[4];
  if (BN) {
    const unsigned int* A32 = (const unsigned int*)Ain;
#pragma unroll
    for (int kb = 0; kb < 4; kb++) {
      uint4 v = *(const uint4*)(A32 + (size_t)arow * 64 + kb * 16 + q * 4);
      unsigned int vv[4] = {v.x, v.y, v.z, v.w};
      short8 t;
#pragma unroll
      for (int j = 0; j < 4; j++) {
        int ch = kb * 32 + q * 8 + j * 2;
        float lo = bf2f(vv[j] & 0xffffu) * scs[ch] + shs[ch];
        float hi = bf2f(vv[j] >> 16) * scs[ch + 1] + shs[ch + 1];
        lo = fmaxf(lo, 0.f); hi = fmaxf(hi, 0.f);
        t[2 * j] = (short)f2bf(lo); t[2 * j + 1] = (short)f2bf(hi);
      }
      a[kb] = t;
    }
  } else {
    const float* Af = (const float*)Ain;
#pragma unroll
    for (int kb = 0; kb < 4; kb++) {
      const float* p = Af + (size_t)arow * 128 + kb * 32 + q * 8;
      float4 v0 = *(const float4*)(p);
      float4 v1 = *(const float4*)(p + 4);
      short8 t;
      t[0] = (short)f2bf(v0.x); t[1] = (short)f2bf(v0.y);
      t[2] = (short)f2bf(v0.z); t[3] = (short)f2bf(v0.w);
      t[4] = (short)f2bf(v1.x); t[5] = (short)f2bf(v1.y);
      t[6] = (short)f2bf(v1.z); t[7] = (short)f2bf(v1.w);
      a[kb] = t;
    }
  }

  f32x4 acc[OUT / 16];
#pragma unroll
  for (int t = 0; t < OUT / 16; t++) acc[t] = (f32x4){0.f, 0.f, 0.f, 0.f};

#pragma unroll
  for (int ot = 0; ot < OUT / 16; ot++) {
    const unsigned short* wrow = Wl + (size_t)(ot * 16 + m) * LDW + q * 8;
    short8 b0 = *(const short8*)(wrow);
    short8 b1 = *(const short8*)(wrow + 32);
    short8 b2 = *(const short8*)(wrow + 64);
    short8 b3 = *(const short8*)(wrow + 96);
    acc[ot] = __builtin_amdgcn_mfma_f32_16x16x32_bf16(a[0], b0, acc[ot], 0, 0, 0);
    acc[ot] = __builtin_amdgcn_mfma_f32_16x16x32_bf16(a[1], b1, acc[ot], 0, 0, 0);
    acc[ot] = __builtin_amdgcn_mfma_f32_16x16x32_bf16(a[2], b2, acc[ot], 0, 0, 0);
    acc[ot] = __builtin_amdgcn_mfma_f32_16x16x32_bf16(a[3], b3, acc[ot], 0, 0, 0);
  }

#pragma unroll
  for (int ot = 0; ot < OUT / 16; ot++) {
#pragma unroll
    for (int r = 0; r < 4; r++) {
      long n = n0 + q * 4 + r;            // D: row = quad*4 + reg, col = lane&15
      if (n < N_NODES) Hb[n * OUT + ot * 16 + m] = f2bf(acc[ot][r]);
    }
  }
}

// ---- aggregation: out[i] = dinv[i] * sum_j dinv[s_j] * Hb[s_j] + bias ----

__global__ __launch_bounds__(256) void agg128_kernel(const unsigned int* __restrict__ H32,
    const int* __restrict__ rs, const unsigned short* __restrict__ csr,
    const float* __restrict__ dinv, const float* __restrict__ bias,
    unsigned int* __restrict__ outb) {
  int lane = threadIdx.x & 63;                  // dword index in row (2 channels)
  int node = blockIdx.x * 4 + (threadIdx.x >> 6);
  if (node >= N_NODES) return;
  int beg = rs[node], end = rs[node + 1];
  float a0x = 0.f, a0y = 0.f, a1x = 0.f, a1y = 0.f;
  float a2x = 0.f, a2y = 0.f, a3x = 0.f, a3y = 0.f;
  int j = beg;
  for (; j + 4 <= end; j += 4) {
    int s0 = csr[j], s1 = csr[j + 1], s2 = csr[j + 2], s3 = csr[j + 3];
    float w0 = dinv[s0], w1 = dinv[s1], w2 = dinv[s2], w3 = dinv[s3];
    unsigned int v0 = H32[(size_t)s0 * 64 + lane];
    unsigned int v1 = H32[(size_t)s1 * 64 + lane];
    unsigned int v2 = H32[(size_t)s2 * 64 + lane];
    unsigned int v3 = H32[(size_t)s3 * 64 + lane];
    a0x += w0 * bf2f(v0 & 0xffffu); a0y += w0 * bf2f(v0 >> 16);
    a1x += w1 * bf2f(v1 & 0xffffu); a1y += w1 * bf2f(v1 >> 16);
    a2x += w2 * bf2f(v2 & 0xffffu); a2y += w2 * bf2f(v2 >> 16);
    a3x += w3 * bf2f(v3 & 0xffffu); a3y += w3 * bf2f(v3 >> 16);
  }
  for (; j < end; ++j) {
    int s0 = csr[j];
    float w0 = dinv[s0];
    unsigned int v0 = H32[(size_t)s0 * 64 + lane];
    a0x += w0 * bf2f(v0 & 0xffffu); a0y += w0 * bf2f(v0 >> 16);
  }
  float di = dinv[node];
  int c = lane * 2;
  float rx = (a0x + a1x + a2x + a3x) * di + bias[c];
  float ry = (a0y + a1y + a2y + a3y) * di + bias[c + 1];
  outb[(size_t)node * 64 + lane] = (unsigned int)f2bf(rx) | ((unsigned int)f2bf(ry) << 16);
}

__global__ __launch_bounds__(256) void agg64_kernel(const unsigned int* __restrict__ H32,
    const int* __restrict__ rs, const unsigned short* __restrict__ csr,
    const float* __restrict__ dinv, const float* __restrict__ bias,
    float* __restrict__ out) {
  int l = threadIdx.x & 31;                     // dword index in row
  int node = blockIdx.x * 8 + (threadIdx.x >> 5);
  if (node >= N_NODES) return;
  int beg = rs[node], end = rs[node + 1];
  float a0x = 0.f, a0y = 0.f, a1x = 0.f, a1y = 0.f;
  float a2x = 0.f, a2y = 0.f, a3x = 0.f, a3y = 0.f;
  int j = beg;
  for (; j + 4 <= end; j += 4) {
    int s0 = csr[j], s1 = csr[j + 1], s2 = csr[j + 2], s3 = csr[j + 3];
    float w0 = dinv[s0], w1 = dinv[s1], w2 = dinv[s2], w3 = dinv[s3];
    unsigned int v0 = H32[(size_t)s0 * 32 + l];
    unsigned int v1 = H32[(size_t)s1 * 32 + l];
    unsigned int v2 = H32[(size_t)s2 * 32 + l];
    unsigned int v3 = H32[(size_t)s3 * 32 + l];
    a0x += w0 * bf2f(v0 & 0xffffu); a0y += w0 * bf2f(v0 >> 16);
    a1x += w1 * bf2f(v1 & 0xffffu); a1y += w1 * bf2f(v1 >> 16);
    a2x += w2 * bf2f(v2 & 0xffffu); a2y += w2 * bf2f(v2 >> 16);
    a3x += w3 * bf2f(v3 & 0xffffu); a3y += w3 * bf2f(v3 >> 16);
  }
  for (; j < end; ++j) {
    int s0 = csr[j];
    float w0 = dinv[s0];
    unsigned int v0 = H32[(size_t)s0 * 32 + l];
    a0x += w0 * bf2f(v0 & 0xffffu); a0y += w0 * bf2f(v0 >> 16);
  }
  float di = dinv[node];
  int c = l * 2;
  out[(size_t)node * 64 + c]     = (a0x + a1x + a2x + a3x) * di + bias[c];
  out[(size_t)node * 64 + c + 1] = (a0y + a1y + a2y + a3y) * di + bias[c + 1];
}

// ---- BN stats over bf16-packed agg output --------------------------------

__global__ __launch_bounds__(256) void stats_kernel(const unsigned int* __restrict__ B32,
                                                    float* __restrict__ sums) {
  __shared__ float lsx[256], lsy[256], l2x[256], l2y[256];
  int tid = threadIdx.x;
  int d = tid & 63, grp = tid >> 6;
  float sx = 0.f, sy = 0.f, qx = 0.f, qy = 0.f;
  for (int r = blockIdx.x * 4 + grp; r < N_NODES; r += gridDim.x * 4) {
    unsigned int v = B32[(size_t)r * 64 + d];
    float x = bf2f(v & 0xffffu), y = bf2f(v >> 16);
    sx += x; sy += y; qx += x * x; qy += y * y;
  }
  lsx[tid] = sx; lsy[tid] = sy; l2x[tid] = qx; l2y[tid] = qy;
  __syncthreads();
  if (tid < 64) {
    float ax = lsx[tid] + lsx[64 + tid] + lsx[128 + tid] + lsx[192 + tid];
    float ay = lsy[tid] + lsy[64 + tid] + lsy[128 + tid] + lsy[192 + tid];
    float bx = l2x[tid] + l2x[64 + tid] + l2x[128 + tid] + l2x[192 + tid];
    float by = l2y[tid] + l2y[64 + tid] + l2y[128 + tid] + l2y[192 + tid];
    atomicAdd(&sums[2 * tid], ax);
    atomicAdd(&sums[2 * tid + 1], ay);
    atomicAdd(&sums[128 + 2 * tid], bx);
    atomicAdd(&sums[128 + 2 * tid + 1], by);
  }
}

// ---- driver --------------------------------------------------------------

extern "C" void kernel_launch(void* const* d_in, const int* in_sizes, int n_in,
                              void* d_out, int out_size, void* d_ws, size_t ws_size,
                              hipStream_t stream) {
  const float* x   = (const float*)d_in[0];
  const int*   ei  = (const int*)d_in[1];
  const float* W1  = (const float*)d_in[2];
  const float* b1  = (const float*)d_in[3];
  const float* W2  = (const float*)d_in[4];
  const float* b2  = (const float*)d_in[5];
  const float* W3  = (const float*)d_in[6];
  const float* b3  = (const float*)d_in[7];
  const float* g1  = (const float*)d_in[8];
  const float* bt1 = (const float*)d_in[9];
  const float* g2  = (const float*)d_in[10];
  const float* bt2 = (const float*)d_in[11];
  float* out = (float*)d_out;

  char* p = (char*)d_ws;
  auto carve = [&](size_t bytes) { char* r = p; p += (bytes + 255) & ~(size_t)255; return r; };
  int*   rs      = (int*)  carve((size_t)(N_NODES + 1) * 4);
  float* dinv    = (float*)carve((size_t)N_NODES * 4);
  int*   cur     = (int*)  carve((size_t)NBUCK * 4);
  int*   csrbase = (int*)  carve((size_t)NBUCK * 4);
  unsigned int* part = (unsigned int*)carve((size_t)NBUCK * BCAP * 4);
  unsigned short* csr = (unsigned short*)carve((size_t)TOT_E * 2);
  float* sums1   = (float*)carve(256 * 4);
  float* sums2   = (float*)carve(256 * 4);
  int*   flag    = (int*)  carve(256);
  unsigned short* Hb = (unsigned short*)carve((size_t)N_NODES * 128 * 2);
  unsigned int*   Bb = (unsigned int*)  carve((size_t)N_NODES * 64 * 4);

  init_kernel<<<(N_NODES + 255) / 256, 256, 0, stream>>>(sums1, sums2, rs, cur, ei, flag);
  part_kernel<<<PART_BLOCKS, 1024, 0, stream>>>(ei, flag, cur, part);
  bscan_kernel<<<1, 512, 0, stream>>>(cur, csrbase);
  fin_kernel<<<NBUCK, 256, 0, stream>>>(part, cur, csrbase, csr, rs, dinv);

  // layer 1: mm(x) -> agg -> stats
  mm_kernel<128, 0><<<(N_NODES + 63) / 64, 256, 0, stream>>>(x, sums1, g1, bt1, W1, Hb);
  agg128_kernel<<<(N_NODES + 3) / 4, 256, 0, stream>>>((const unsigned int*)Hb, rs, csr, dinv, b1, Bb);
  stats_kernel<<<512, 256, 0, stream>>>(Bb, sums1);

  // layer 2: mm(BN1(Bb)) -> agg -> stats
  mm_kernel<128, 1><<<(N_NODES + 63) / 64, 256, 0, stream>>>(Bb, sums1, g1, bt1, W2, Hb);
  agg128_kernel<<<(N_NODES + 3) / 4, 256, 0, stream>>>((const unsigned int*)Hb, rs, csr, dinv, b2, Bb);
  stats_kernel<<<512, 256, 0, stream>>>(Bb, sums2);

  // layer 3: mm(BN2(Bb)) -> agg -> out (fp32)
  mm_kernel<64, 1><<<(N_NODES + 63) / 64, 256, 0, stream>>>(Bb, sums2, g2, bt2, W3, Hb);
  agg64_kernel<<<(N_NODES + 7) / 8, 256, 0, stream>>>((const unsigned int*)Hb, rs, csr, dinv, b3, out);
}

// Round 5
// 303.266 us; speedup vs baseline: 1.8654x; 1.1631x over previous
//
#include <hip/hip_runtime.h>
#include <hip/hip_bf16.h>

#define N_NODES 50000
#define N_EDGES 800000
#define TOT_E   (N_EDGES + N_NODES)
#define NBUCK   ((N_NODES + 127) / 128)     // 391 buckets of 128 dst nodes
#define BCAP    3072                         // bucket capacity (avg 2048, max ~2300)
#define PART_BLOCKS 256
#define EPB     (N_EDGES / PART_BLOCKS)      // 3125 edges per partition block

typedef __attribute__((ext_vector_type(8))) short short8;
typedef __attribute__((ext_vector_type(4))) float f32x4;

__device__ __forceinline__ unsigned short f2bf(float f) {
  union { float f; unsigned int u; } x; x.f = f;
  unsigned int u = x.u;
  unsigned int r = (u + 0x7FFFu + ((u >> 16) & 1u)) >> 16;  // RNE
  return (unsigned short)r;
}
__device__ __forceinline__ float bf2f(unsigned int u16) {
  union { unsigned int u; float f; } x; x.u = u16 << 16; return x.f;
}

// ---- init: zero sums, bucket cursors, rs[N], dtype-detect flag -----------

__global__ void init_kernel(float* __restrict__ sums1, float* __restrict__ sums2,
                            int* __restrict__ rs, int* __restrict__ cur,
                            const int* __restrict__ ei, int* __restrict__ flag) {
  int i = blockIdx.x * 256 + threadIdx.x;
  if (i < 256) { sums1[i] = 0.f; sums2[i] = 0.f; }
  if (i < NBUCK) cur[i] = i * BCAP;
  if (i == 0) rs[N_NODES] = TOT_E;
  // int64 detection: odd int32 words of first 64 entries all zero => int64
  if (blockIdx.x == 0 && threadIdx.x < 64) {
    int v = ei[2 * threadIdx.x + 1];
    unsigned long long b = __ballot(v != 0);
    if (threadIdx.x == 0) flag[0] = (b == 0ULL) ? 1 : 0;
  }
}

// ---- partition: bucket edges by dst>>7, LDS-sorted coalesced flush -------

__global__ __launch_bounds__(1024) void part_kernel(const int* __restrict__ ei,
    const int* __restrict__ flag, int* __restrict__ cur, unsigned int* __restrict__ part) {
  __shared__ int hist[NBUCK];
  __shared__ int hist2[NBUCK];
  __shared__ int lexcl[NBUCK];
  __shared__ int gbase[NBUCK];
  __shared__ int wtot[8];
  __shared__ unsigned int sorted[EPB];
  int tid = threadIdx.x;
  int e0 = blockIdx.x * EPB;
  for (int i = tid; i < NBUCK; i += 1024) { hist[i] = 0; hist2[i] = 0; }
  __syncthreads();
  bool i64 = flag[0] != 0;
  // pass 1: bucket histogram
  for (int i = tid; i < EPB; i += 1024) {
    int e = e0 + i;
    int d = i64 ? ei[2 * (N_EDGES + e)] : ei[N_EDGES + e];
    atomicAdd(&hist[d >> 7], 1);
  }
  __syncthreads();
  // exclusive scan of hist -> lexcl (NBUCK <= 512: 8 waves)
  if (tid < 512) {
    int lane = tid & 63, w = tid >> 6;
    int h = (tid < NBUCK) ? hist[tid] : 0;
    int v = h;
#pragma unroll
    for (int off = 1; off < 64; off <<= 1) {
      int u = __shfl_up(v, off);
      if (lane >= off) v += u;
    }
    if (lane == 63) wtot[w] = v;
    if (tid < NBUCK) lexcl[tid] = v - h;
  }
  __syncthreads();
  if (tid < NBUCK) {
    int w = tid >> 6, off = 0;
    for (int k = 0; k < w; k++) off += wtot[k];
    lexcl[tid] += off;
    gbase[tid] = atomicAdd(&cur[tid], hist[tid]);   // reserve global range
  }
  __syncthreads();
  // pass 2: stage edges sorted by bucket in LDS
  for (int i = tid; i < EPB; i += 1024) {
    int e = e0 + i;
    int s, d;
    if (i64) { s = ei[2 * e]; d = ei[2 * (N_EDGES + e)]; }
    else     { s = ei[e];     d = ei[N_EDGES + e]; }
    int b = d >> 7;
    int ls = atomicAdd(&hist2[b], 1);
    sorted[lexcl[b] + ls] = ((unsigned int)d << 16) | (unsigned int)s;
  }
  __syncthreads();
  // flush: consecutive tid -> consecutive slots within bucket (coalesced runs)
  for (int j = tid; j < EPB; j += 1024) {
    unsigned int pk = sorted[j];
    int b = (int)(pk >> 23);                      // (d>>16)>>7
    part[gbase[b] + (j - lexcl[b])] = pk;
  }
}

// ---- finalize: per-bucket CSR (ushort), rs, dinv; bscan folded in --------

__global__ __launch_bounds__(256) void fin_kernel(const unsigned int* __restrict__ part,
    const int* __restrict__ cur, unsigned short* __restrict__ csr,
    int* __restrict__ rs, float* __restrict__ dinv) {
  __shared__ int cnt[128], excl[128], iscan[128];
  __shared__ int redbuf[256];
  __shared__ unsigned short ord[BCAP];
  __shared__ unsigned short cls[BCAP + 128];
  int b = blockIdx.x, tid = threadIdx.x;
  int n0 = b * 128;
  int nn = N_NODES - n0; if (nn > 128) nn = 128;
  int ecnt = cur[b] - b * BCAP; if (ecnt > BCAP) ecnt = BCAP;
  int ebase = b * BCAP;
  // csrbase reduction: sum real counts of buckets < b (+128 self-loops each)
  int partial = 0;
  for (int i = tid; i < b; i += 256) partial += cur[i] - i * BCAP + 128;
  redbuf[tid] = partial;
  if (tid < 128) cnt[tid] = 1;                    // self-loop
  __syncthreads();
  if (tid < 128) redbuf[tid] += redbuf[tid + 128];
  for (int i = tid; i < ecnt; i += 256) {
    int dl = (int)((part[ebase + i] >> 16) & 127u);
    ord[i] = (unsigned short)atomicAdd(&cnt[dl], 1);
  }
  __syncthreads();
  // finish reduction with wave 0
  if (tid < 64) {
    int v = redbuf[tid] + redbuf[tid + 64];
#pragma unroll
    for (int off = 32; off; off >>= 1) v += __shfl_xor(v, off);
    redbuf[0] = v;
  }
  // exclusive scan of cnt[0..128): 2 waves
  if (tid >= 128 && tid < 256) {
    int t2 = tid - 128;
    int lane = t2 & 63;
    int c = cnt[t2], v = c;
#pragma unroll
    for (int off = 1; off < 64; off <<= 1) {
      int u = __shfl_up(v, off);
      if (lane >= off) v += u;
    }
    iscan[t2] = v;
  }
  __syncthreads();
  if (tid < 128)
    excl[tid] = iscan[tid] - cnt[tid] + ((tid >= 64) ? iscan[63] : 0);
  __syncthreads();
  int base = redbuf[0];
  // place self-loops then edges
  if (tid < nn) cls[excl[tid]] = (unsigned short)(n0 + tid);
  __syncthreads();
  for (int i = tid; i < ecnt; i += 256) {
    unsigned int pk = part[ebase + i];
    int dl = (int)((pk >> 16) & 127u);
    cls[excl[dl] + ord[i]] = (unsigned short)(pk & 0xffffu);
  }
  __syncthreads();
  int tot = ecnt + nn;
  for (int j = tid; j < tot; j += 256) csr[base + j] = cls[j];
  if (tid < nn) {
    rs[n0 + tid] = base + excl[tid];
    dinv[n0 + tid] = rsqrtf((float)cnt[tid]);
  }
}

// ---- dense matmul with fused A-side BN/ReLU/bf16 cast --------------------
// BN==0: A is fp32 [N][128] raw (layer 1 input x).
// BN==1: A is bf16-packed dwords [N][64] (prev agg out); apply BN+ReLU.
// Epilogue folds dinv: Hb[n][o] = bf16( dinv[n] * sum_k a(n,k)*W[o][k] )

template <int OUT, int BN>
__global__ __launch_bounds__(256) void mm_kernel(const void* __restrict__ Ain,
    const float* __restrict__ sums, const float* __restrict__ g,
    const float* __restrict__ bt, const float* __restrict__ W,
    const float* __restrict__ dinv, unsigned short* __restrict__ Hb) {
  constexpr int K = 128;
  constexpr int LDW = K + 8;
  __shared__ __align__(16) unsigned short Wl[OUT * LDW];
  __shared__ float scs[128], shs[128];
  int tid = threadIdx.x;
  for (int i = tid; i < OUT * K; i += 256)
    Wl[(i >> 7) * LDW + (i & 127)] = f2bf(W[i]);
  if (BN && tid < 128) {
    const float inv_n = 1.0f / (float)N_NODES;
    float mean = sums[tid] * inv_n;
    float var  = sums[128 + tid] * inv_n - mean * mean;
    float sc = g[tid] * rsqrtf(var + 1e-5f);
    scs[tid] = sc;
    shs[tid] = bt[tid] - mean * sc;
  }
  __syncthreads();

  int lane = tid & 63;
  int wv = tid >> 6;
  int m = lane & 15, q = lane >> 4;
  long n0 = (long)blockIdx.x * 64 + wv * 16;
  long arow = n0 + m; if (arow > N_NODES - 1) arow = N_NODES - 1;

  short8 a[4];
  if (BN) {
    const unsigned int* A32 = (const unsigned int*)Ain;
#pragma unroll
    for (int kb = 0; kb < 4; kb++) {
      uint4 v = *(const uint4*)(A32 + (size_t)arow * 64 + kb * 16 + q * 4);
      unsigned int vv[4] = {v.x, v.y, v.z, v.w};
      short8 t;
#pragma unroll
      for (int j = 0; j < 4; j++) {
        int ch = kb * 32 + q * 8 + j * 2;
        float lo = bf2f(vv[j] & 0xffffu) * scs[ch] + shs[ch];
        float hi = bf2f(vv[j] >> 16) * scs[ch + 1] + shs[ch + 1];
        lo = fmaxf(lo, 0.f); hi = fmaxf(hi, 0.f);
        t[2 * j] = (short)f2bf(lo); t[2 * j + 1] = (short)f2bf(hi);
      }
      a[kb] = t;
    }
  } else {
    const float* Af = (const float*)Ain;
#pragma unroll
    for (int kb = 0; kb < 4; kb++) {
      const float* p = Af + (size_t)arow * 128 + kb * 32 + q * 8;
      float4 v0 = *(const float4*)(p);
      float4 v1 = *(const float4*)(p + 4);
      short8 t;
      t[0] = (short)f2bf(v0.x); t[1] = (short)f2bf(v0.y);
      t[2] = (short)f2bf(v0.z); t[3] = (short)f2bf(v0.w);
      t[4] = (short)f2bf(v1.x); t[5] = (short)f2bf(v1.y);
      t[6] = (short)f2bf(v1.z); t[7] = (short)f2bf(v1.w);
      a[kb] = t;
    }
  }

  f32x4 acc[OUT / 16];
#pragma unroll
  for (int t = 0; t < OUT / 16; t++) acc[t] = (f32x4){0.f, 0.f, 0.f, 0.f};

#pragma unroll
  for (int ot = 0; ot < OUT / 16; ot++) {
    const unsigned short* wrow = Wl + (size_t)(ot * 16 + m) * LDW + q * 8;
    short8 b0 = *(const short8*)(wrow);
    short8 b1 = *(const short8*)(wrow + 32);
    short8 b2 = *(const short8*)(wrow + 64);
    short8 b3 = *(const short8*)(wrow + 96);
    acc[ot] = __builtin_amdgcn_mfma_f32_16x16x32_bf16(a[0], b0, acc[ot], 0, 0, 0);
    acc[ot] = __builtin_amdgcn_mfma_f32_16x16x32_bf16(a[1], b1, acc[ot], 0, 0, 0);
    acc[ot] = __builtin_amdgcn_mfma_f32_16x16x32_bf16(a[2], b2, acc[ot], 0, 0, 0);
    acc[ot] = __builtin_amdgcn_mfma_f32_16x16x32_bf16(a[3], b3, acc[ot], 0, 0, 0);
  }

  float dn[4];
#pragma unroll
  for (int r = 0; r < 4; r++) {
    long n = n0 + q * 4 + r;
    dn[r] = (n < N_NODES) ? dinv[n] : 0.f;
  }
#pragma unroll
  for (int ot = 0; ot < OUT / 16; ot++) {
#pragma unroll
    for (int r = 0; r < 4; r++) {
      long n = n0 + q * 4 + r;            // D: row = quad*4 + reg, col = lane&15
      if (n < N_NODES) Hb[n * OUT + ot * 16 + m] = f2bf(dn[r] * acc[ot][r]);
    }
  }
}

// ---- aggregation: out[i] = dinv[i] * sum_j Hb[s_j] + bias ----------------
// (dinv[s] pre-folded into Hb rows). 8-wide gather unroll.

__global__ __launch_bounds__(256) void agg128_kernel(const unsigned int* __restrict__ H32,
    const int* __restrict__ rs, const unsigned short* __restrict__ csr,
    const float* __restrict__ dinv, const float* __restrict__ bias,
    unsigned int* __restrict__ outb) {
  int lane = threadIdx.x & 63;                  // dword index in row (2 channels)
  int node = blockIdx.x * 4 + (threadIdx.x >> 6);
  if (node >= N_NODES) return;
  int beg = rs[node], end = rs[node + 1];
  float sx = 0.f, sy = 0.f, tx = 0.f, ty = 0.f;
  int j = beg;
  for (; j + 8 <= end; j += 8) {
    int s0 = csr[j],     s1 = csr[j + 1], s2 = csr[j + 2], s3 = csr[j + 3];
    int s4 = csr[j + 4], s5 = csr[j + 5], s6 = csr[j + 6], s7 = csr[j + 7];
    unsigned int v0 = H32[(size_t)s0 * 64 + lane];
    unsigned int v1 = H32[(size_t)s1 * 64 + lane];
    unsigned int v2 = H32[(size_t)s2 * 64 + lane];
    unsigned int v3 = H32[(size_t)s3 * 64 + lane];
    unsigned int v4 = H32[(size_t)s4 * 64 + lane];
    unsigned int v5 = H32[(size_t)s5 * 64 + lane];
    unsigned int v6 = H32[(size_t)s6 * 64 + lane];
    unsigned int v7 = H32[(size_t)s7 * 64 + lane];
    sx += bf2f(v0 & 0xffffu) + bf2f(v1 & 0xffffu) + bf2f(v2 & 0xffffu) + bf2f(v3 & 0xffffu);
    sy += bf2f(v0 >> 16)     + bf2f(v1 >> 16)     + bf2f(v2 >> 16)     + bf2f(v3 >> 16);
    tx += bf2f(v4 & 0xffffu) + bf2f(v5 & 0xffffu) + bf2f(v6 & 0xffffu) + bf2f(v7 & 0xffffu);
    ty += bf2f(v4 >> 16)     + bf2f(v5 >> 16)     + bf2f(v6 >> 16)     + bf2f(v7 >> 16);
  }
  if (j + 4 <= end) {
    int s0 = csr[j], s1 = csr[j + 1], s2 = csr[j + 2], s3 = csr[j + 3];
    unsigned int v0 = H32[(size_t)s0 * 64 + lane];
    unsigned int v1 = H32[(size_t)s1 * 64 + lane];
    unsigned int v2 = H32[(size_t)s2 * 64 + lane];
    unsigned int v3 = H32[(size_t)s3 * 64 + lane];
    sx += bf2f(v0 & 0xffffu) + bf2f(v1 & 0xffffu) + bf2f(v2 & 0xffffu) + bf2f(v3 & 0xffffu);
    sy += bf2f(v0 >> 16)     + bf2f(v1 >> 16)     + bf2f(v2 >> 16)     + bf2f(v3 >> 16);
    j += 4;
  }
  for (; j < end; ++j) {
    unsigned int v0 = H32[(size_t)csr[j] * 64 + lane];
    tx += bf2f(v0 & 0xffffu); ty += bf2f(v0 >> 16);
  }
  float di = dinv[node];
  int c = lane * 2;
  float rx = (sx + tx) * di + bias[c];
  float ry = (sy + ty) * di + bias[c + 1];
  outb[(size_t)node * 64 + lane] = (unsigned int)f2bf(rx) | ((unsigned int)f2bf(ry) << 16);
}

__global__ __launch_bounds__(256) void agg64_kernel(const unsigned int* __restrict__ H32,
    const int* __restrict__ rs, const unsigned short* __restrict__ csr,
    const float* __restrict__ dinv, const float* __restrict__ bias,
    float* __restrict__ out) {
  int l = threadIdx.x & 31;                     // dword index in row
  int node = blockIdx.x * 8 + (threadIdx.x >> 5);
  if (node >= N_NODES) return;
  int beg = rs[node], end = rs[node + 1];
  float sx = 0.f, sy = 0.f, tx = 0.f, ty = 0.f;
  int j = beg;
  for (; j + 8 <= end; j += 8) {
    int s0 = csr[j],     s1 = csr[j + 1], s2 = csr[j + 2], s3 = csr[j + 3];
    int s4 = csr[j + 4], s5 = csr[j + 5], s6 = csr[j + 6], s7 = csr[j + 7];
    unsigned int v0 = H32[(size_t)s0 * 32 + l];
    unsigned int v1 = H32[(size_t)s1 * 32 + l];
    unsigned int v2 = H32[(size_t)s2 * 32 + l];
    unsigned int v3 = H32[(size_t)s3 * 32 + l];
    unsigned int v4 = H32[(size_t)s4 * 32 + l];
    unsigned int v5 = H32[(size_t)s5 * 32 + l];
    unsigned int v6 = H32[(size_t)s6 * 32 + l];
    unsigned int v7 = H32[(size_t)s7 * 32 + l];
    sx += bf2f(v0 & 0xffffu) + bf2f(v1 & 0xffffu) + bf2f(v2 & 0xffffu) + bf2f(v3 & 0xffffu);
    sy += bf2f(v0 >> 16)     + bf2f(v1 >> 16)     + bf2f(v2 >> 16)     + bf2f(v3 >> 16);
    tx += bf2f(v4 & 0xffffu) + bf2f(v5 & 0xffffu) + bf2f(v6 & 0xffffu) + bf2f(v7 & 0xffffu);
    ty += bf2f(v4 >> 16)     + bf2f(v5 >> 16)     + bf2f(v6 >> 16)     + bf2f(v7 >> 16);
  }
  if (j + 4 <= end) {
    int s0 = csr[j], s1 = csr[j + 1], s2 = csr[j + 2], s3 = csr[j + 3];
    unsigned int v0 = H32[(size_t)s0 * 32 + l];
    unsigned int v1 = H32[(size_t)s1 * 32 + l];
    unsigned int v2 = H32[(size_t)s2 * 32 + l];
    unsigned int v3 = H32[(size_t)s3 * 32 + l];
    sx += bf2f(v0 & 0xffffu) + bf2f(v1 & 0xffffu) + bf2f(v2 & 0xffffu) + bf2f(v3 & 0xffffu);
    sy += bf2f(v0 >> 16)     + bf2f(v1 >> 16)     + bf2f(v2 >> 16)     + bf2f(v3 >> 16);
    j += 4;
  }
  for (; j < end; ++j) {
    unsigned int v0 = H32[(size_t)csr[j] * 32 + l];
    tx += bf2f(v0 & 0xffffu); ty += bf2f(v0 >> 16);
  }
  float di = dinv[node];
  int c = l * 2;
  out[(size_t)node * 64 + c]     = (sx + tx) * di + bias[c];
  out[(size_t)node * 64 + c + 1] = (sy + ty) * di + bias[c + 1];
}

// ---- BN stats over bf16-packed agg output --------------------------------

__global__ __launch_bounds__(256) void stats_kernel(const unsigned int* __restrict__ B32,
                                                    float* __restrict__ sums) {
  __shared__ float lsx[256], lsy[256], l2x[256], l2y[256];
  int tid = threadIdx.x;
  int d = tid & 63, grp = tid >> 6;
  float sx = 0.f, sy = 0.f, qx = 0.f, qy = 0.f;
  for (int r = blockIdx.x * 4 + grp; r < N_NODES; r += gridDim.x * 4) {
    unsigned int v = B32[(size_t)r * 64 + d];
    float x = bf2f(v & 0xffffu), y = bf2f(v >> 16);
    sx += x; sy += y; qx += x * x; qy += y * y;
  }
  lsx[tid] = sx; lsy[tid] = sy; l2x[tid] = qx; l2y[tid] = qy;
  __syncthreads();
  if (tid < 64) {
    float ax = lsx[tid] + lsx[64 + tid] + lsx[128 + tid] + lsx[192 + tid];
    float ay = lsy[tid] + lsy[64 + tid] + lsy[128 + tid] + lsy[192 + tid];
    float bx = l2x[tid] + l2x[64 + tid] + l2x[128 + tid] + l2x[192 + tid];
    float by = l2y[tid] + l2y[64 + tid] + l2y[128 + tid] + l2y[192 + tid];
    atomicAdd(&sums[2 * tid], ax);
    atomicAdd(&sums[2 * tid + 1], ay);
    atomicAdd(&sums[128 + 2 * tid], bx);
    atomicAdd(&sums[128 + 2 * tid + 1], by);
  }
}

// ---- driver --------------------------------------------------------------

extern "C" void kernel_launch(void* const* d_in, const int* in_sizes, int n_in,
                              void* d_out, int out_size, void* d_ws, size_t ws_size,
                              hipStream_t stream) {
  const float* x   = (const float*)d_in[0];
  const int*   ei  = (const int*)d_in[1];
  const float* W1  = (const float*)d_in[2];
  const float* b1  = (const float*)d_in[3];
  const float* W2  = (const float*)d_in[4];
  const float* b2  = (const float*)d_in[5];
  const float* W3  = (const float*)d_in[6];
  const float* b3  = (const float*)d_in[7];
  const float* g1  = (const float*)d_in[8];
  const float* bt1 = (const float*)d_in[9];
  const float* g2  = (const float*)d_in[10];
  const float* bt2 = (const float*)d_in[11];
  float* out = (float*)d_out;

  char* p = (char*)d_ws;
  auto carve = [&](size_t bytes) { char* r = p; p += (bytes + 255) & ~(size_t)255; return r; };
  int*   rs      = (int*)  carve((size_t)(N_NODES + 1) * 4);
  float* dinv    = (float*)carve((size_t)N_NODES * 4);
  int*   cur     = (int*)  carve((size_t)NBUCK * 4);
  unsigned int* part = (unsigned int*)carve((size_t)NBUCK * BCAP * 4);
  unsigned short* csr = (unsigned short*)carve((size_t)TOT_E * 2);
  float* sums1   = (float*)carve(256 * 4);
  float* sums2   = (float*)carve(256 * 4);
  int*   flag    = (int*)  carve(256);
  unsigned short* Hb = (unsigned short*)carve((size_t)N_NODES * 128 * 2);
  unsigned int*   Bb = (unsigned int*)  carve((size_t)N_NODES * 64 * 4);

  init_kernel<<<(N_NODES + 255) / 256, 256, 0, stream>>>(sums1, sums2, rs, cur, ei, flag);
  part_kernel<<<PART_BLOCKS, 1024, 0, stream>>>(ei, flag, cur, part);
  fin_kernel<<<NBUCK, 256, 0, stream>>>(part, cur, csr, rs, dinv);

  // layer 1: mm(x) -> agg -> stats
  mm_kernel<128, 0><<<(N_NODES + 63) / 64, 256, 0, stream>>>(x, sums1, g1, bt1, W1, dinv, Hb);
  agg128_kernel<<<(N_NODES + 3) / 4, 256, 0, stream>>>((const unsigned int*)Hb, rs, csr, dinv, b1, Bb);
  stats_kernel<<<512, 256, 0, stream>>>(Bb, sums1);

  // layer 2: mm(BN1(Bb)) -> agg -> stats
  mm_kernel<128, 1><<<(N_NODES + 63) / 64, 256, 0, stream>>>(Bb, sums1, g1, bt1, W2, dinv, Hb);
  agg128_kernel<<<(N_NODES + 3) / 4, 256, 0, stream>>>((const unsigned int*)Hb, rs, csr, dinv, b2, Bb);
  stats_kernel<<<512, 256, 0, stream>>>(Bb, sums2);

  // layer 3: mm(BN2(Bb)) -> agg -> out (fp32)
  mm_kernel<64, 1><<<(N_NODES + 63) / 64, 256, 0, stream>>>(Bb, sums2, g2, bt2, W3, dinv, Hb);
  agg64_kernel<<<(N_NODES + 7) / 8, 256, 0, stream>>>((const unsigned int*)Hb, rs, csr, dinv, b3, out);
}